// Round 1
// baseline (990.355 us; speedup 1.0000x reference)
//
#include <hip/hip_runtime.h>
#include <hip/hip_bf16.h>
#include <math.h>

// Problem constants
#define NN 8192
#define HH 256
#define KK 128
#define BB 64
#define LL 128

// ---------------------------------------------------------------------------
// Generic tiled fp32 GEMM: C[m][n] = sum_k A[row(m)][k] * B[k][n] (+bias, relu)
// BM=BN=64, BK=16, 256 threads, 4x4 micro-tile per thread.
// ---------------------------------------------------------------------------
template<int RELU, int BIAS, int GATHER>
__global__ __launch_bounds__(256) void gemm_f32(
    const float* __restrict__ Ag, const float* __restrict__ Bg,
    float* __restrict__ Cg, const float* __restrict__ bias,
    const int* __restrict__ rowidx, int M, int N, int Kd)
{
    __shared__ __align__(16) float As[16][68];
    __shared__ __align__(16) float Bs[16][68];
    const int tid = threadIdx.x;
    const int tx = tid & 15, ty = tid >> 4;
    const int m0 = blockIdx.y * 64, n0 = blockIdx.x * 64;

    const int lk = tid & 15;        // A-load k within chunk
    const int lmb = tid >> 4;       // A-load m base (0..15)
    const int nb = tid & 63;        // B-load n
    const int kb = tid >> 6;        // B-load k base (0..3)

    long arow[4];
#pragma unroll
    for (int i = 0; i < 4; i++) {
        int m = m0 + lmb + i * 16;
        int r = GATHER ? rowidx[m] : m;
        arow[i] = (long)r * Kd;
    }

    float acc[4][4] = {};

    for (int k0 = 0; k0 < Kd; k0 += 16) {
#pragma unroll
        for (int i = 0; i < 4; i++)
            As[lk][lmb + i * 16] = Ag[arow[i] + k0 + lk];
#pragma unroll
        for (int i = 0; i < 4; i++)
            Bs[kb + i * 4][nb] = Bg[(long)(k0 + kb + i * 4) * N + n0 + nb];
        __syncthreads();
#pragma unroll
        for (int k = 0; k < 16; k++) {
            float4 av = *(const float4*)&As[k][ty * 4];
            float4 bv = *(const float4*)&Bs[k][tx * 4];
            float a0 = av.x, a1 = av.y, a2 = av.z, a3 = av.w;
            float b0 = bv.x, b1 = bv.y, b2 = bv.z, b3 = bv.w;
            acc[0][0] = fmaf(a0, b0, acc[0][0]); acc[0][1] = fmaf(a0, b1, acc[0][1]);
            acc[0][2] = fmaf(a0, b2, acc[0][2]); acc[0][3] = fmaf(a0, b3, acc[0][3]);
            acc[1][0] = fmaf(a1, b0, acc[1][0]); acc[1][1] = fmaf(a1, b1, acc[1][1]);
            acc[1][2] = fmaf(a1, b2, acc[1][2]); acc[1][3] = fmaf(a1, b3, acc[1][3]);
            acc[2][0] = fmaf(a2, b0, acc[2][0]); acc[2][1] = fmaf(a2, b1, acc[2][1]);
            acc[2][2] = fmaf(a2, b2, acc[2][2]); acc[2][3] = fmaf(a2, b3, acc[2][3]);
            acc[3][0] = fmaf(a3, b0, acc[3][0]); acc[3][1] = fmaf(a3, b1, acc[3][1]);
            acc[3][2] = fmaf(a3, b2, acc[3][2]); acc[3][3] = fmaf(a3, b3, acc[3][3]);
        }
        __syncthreads();
    }

#pragma unroll
    for (int i = 0; i < 4; i++) {
        int m = m0 + ty * 4 + i;
        float4 o;
        float v0 = acc[i][0], v1 = acc[i][1], v2 = acc[i][2], v3 = acc[i][3];
        int n = n0 + tx * 4;
        if (BIAS) { v0 += bias[n]; v1 += bias[n + 1]; v2 += bias[n + 2]; v3 += bias[n + 3]; }
        if (RELU) { v0 = fmaxf(v0, 0.f); v1 = fmaxf(v1, 0.f); v2 = fmaxf(v2, 0.f); v3 = fmaxf(v3, 0.f); }
        o.x = v0; o.y = v1; o.z = v2; o.w = v3;
        *(float4*)&Cg[(long)m * N + n] = o;
    }
}

// ---------------------------------------------------------------------------
// Pack weights: WcT[h][o] = Wc[o][h];  Wcat[d][c]: c<128 -> W1[k=c][d],
// c in [128,256) -> W2[k][0][d], c in [256,384) -> W2[k][1][d]
// ---------------------------------------------------------------------------
__global__ void pack_w(const float* __restrict__ Wc, float* __restrict__ WcT,
                       const float* __restrict__ W1, const float* __restrict__ W2,
                       float* __restrict__ Wcat)
{
    int i = blockIdx.x * blockDim.x + threadIdx.x;
    if (i < 256 * 256) {
        int o = i / 256, h = i % 256;
        WcT[h * 256 + o] = Wc[i];
    }
    if (i < 512 * 384) {
        int d = i / 384, c = i % 384;
        int k = c & 127, g = c >> 7;
        float v = (g == 0) ? W1[k * 512 + d] : W2[k * 1024 + (g - 1) * 512 + d];
        Wcat[i] = v;
    }
}

// ---------------------------------------------------------------------------
// Attention q-side: per (b,q): s row, softmax over k, eq row. Stores raw s.
// 128 threads.
// ---------------------------------------------------------------------------
__global__ __launch_bounds__(128) void attn_q(
    const float* __restrict__ Qm, const float* __restrict__ Am,
    float* __restrict__ s, float* __restrict__ eq)
{
    const int b = blockIdx.x >> 7, q = blockIdx.x & 127;
    const int t = threadIdx.x;
    __shared__ float qrow[256];
    __shared__ float p[128];
    __shared__ float red[2];

    const long qoff = ((long)b * 128 + q) * 256;
    qrow[t] = Qm[qoff + t];
    qrow[t + 128] = Qm[qoff + 128 + t];
    __syncthreads();

    const float4* arow4 = (const float4*)(Am + ((long)b * 128 + t) * 256);
    float acc = 0.f;
#pragma unroll 8
    for (int h4 = 0; h4 < 64; h4++) {
        float4 av = arow4[h4];
        acc += qrow[h4 * 4 + 0] * av.x + qrow[h4 * 4 + 1] * av.y +
               qrow[h4 * 4 + 2] * av.z + qrow[h4 * 4 + 3] * av.w;
    }
    s[((long)b * 128 + q) * 128 + t] = acc;

    // softmax over the 128 values (one per thread, 2 waves)
    float m = acc;
#pragma unroll
    for (int off = 32; off; off >>= 1) m = fmaxf(m, __shfl_xor(m, off));
    if ((t & 63) == 0) red[t >> 6] = m;
    __syncthreads();
    m = fmaxf(red[0], red[1]);
    float ex = expf(acc - m);
    float ssum = ex;
#pragma unroll
    for (int off = 32; off; off >>= 1) ssum += __shfl_xor(ssum, off);
    __syncthreads();
    if ((t & 63) == 0) red[t >> 6] = ssum;
    __syncthreads();
    ssum = red[0] + red[1];
    p[t] = ex / ssum;
    __syncthreads();

    float e0 = 0.f, e1 = 0.f;
    for (int k = 0; k < 128; k++) {
        float pv = p[k];
        const float* ar = Am + ((long)b * 128 + k) * 256;
        e0 = fmaf(pv, ar[t], e0);
        e1 = fmaf(pv, ar[t + 128], e1);
    }
    eq[qoff + t] = e0;
    eq[qoff + t + 128] = e1;
}

// ---------------------------------------------------------------------------
// Attention a-side: per (b,k): read s column, softmax over q, ea row.
// ---------------------------------------------------------------------------
__global__ __launch_bounds__(128) void attn_a(
    const float* __restrict__ Qm, const float* __restrict__ s,
    float* __restrict__ ea)
{
    const int b = blockIdx.x >> 7, k = blockIdx.x & 127;
    const int t = threadIdx.x;
    __shared__ float p[128];
    __shared__ float red[2];

    float sv = s[((long)b * 128 + t) * 128 + k];
    float m = sv;
#pragma unroll
    for (int off = 32; off; off >>= 1) m = fmaxf(m, __shfl_xor(m, off));
    if ((t & 63) == 0) red[t >> 6] = m;
    __syncthreads();
    m = fmaxf(red[0], red[1]);
    float ex = expf(sv - m);
    float ssum = ex;
#pragma unroll
    for (int off = 32; off; off >>= 1) ssum += __shfl_xor(ssum, off);
    __syncthreads();
    if ((t & 63) == 0) red[t >> 6] = ssum;
    __syncthreads();
    ssum = red[0] + red[1];
    p[t] = ex / ssum;
    __syncthreads();

    float e0 = 0.f, e1 = 0.f;
    for (int q = 0; q < 128; q++) {
        float pv = p[q];
        const float* qr = Qm + ((long)b * 128 + q) * 256;
        e0 = fmaf(pv, qr[t], e0);
        e1 = fmaf(pv, qr[t + 128], e1);
    }
    const long aoff = ((long)b * 128 + k) * 256;
    ea[aoff + t] = e0;
    ea[aoff + t + 128] = e1;
}

// ---------------------------------------------------------------------------
// t features: t[bl, h] = (X-E)^2, t[bl, 256+h] = X*E
// ---------------------------------------------------------------------------
__global__ void build_t(const float* __restrict__ X, const float* __restrict__ E,
                        float* __restrict__ t)
{
    int i = blockIdx.x * blockDim.x + threadIdx.x;   // over B*L*H = 8192*256
    if (i >= NN * HH / 4 * 4 && i >= BB * LL * HH) return;
    if (i >= BB * LL * HH) return;
    int h = i & 255;
    int bl = i >> 8;
    float x = X[i], e = E[i];
    float d = x - e;
    t[(long)bl * 512 + h] = d * d;
    t[(long)bl * 512 + 256 + h] = x * e;
}

// ---------------------------------------------------------------------------
// Pool: re[b, 0:128]=e1_q, [128:256]=e2_q, [256:384]=e1_a, [384:512]=e2_a
// u layout per (b,l): [0:128) fs1, [128:256) tap0, [256:384) tap1
// ---------------------------------------------------------------------------
__global__ __launch_bounds__(256) void pool_re(
    const float* __restrict__ u_q, const float* __restrict__ u_a,
    const float* __restrict__ b1, const float* __restrict__ b2,
    float* __restrict__ re)
{
    const int b = blockIdx.x;
    const int t = threadIdx.x;
#pragma unroll
    for (int side = 0; side < 2; side++) {
        const float* uu = side ? u_a : u_q;
        if (t < 128) {
            int k = t;
            float bias = b1[k];
            float mx = -1e30f;
            for (int l = 0; l < 128; l++) {
                float v = uu[((long)b * 128 + l) * 384 + k] + bias;
                mx = fmaxf(mx, v);
            }
            mx = fmaxf(mx, 0.f);
            re[b * 512 + side * 256 + k] = mx;
        } else {
            int k = t - 128;
            float bias = b2[k];
            float mx = -1e30f;
            for (int l = 0; l < 127; l++) {
                float v = uu[((long)b * 128 + l) * 384 + 128 + k]
                        + uu[((long)b * 128 + l + 1) * 384 + 256 + k] + bias;
                mx = fmaxf(mx, v);
            }
            mx = fmaxf(mx, 0.f);
            re[b * 512 + side * 256 + 128 + k] = mx;
        }
    }
}

// ---------------------------------------------------------------------------
// Final: out[b,:] = log_softmax(re[b] @ Wd^T + bd)
// ---------------------------------------------------------------------------
__global__ __launch_bounds__(64) void final_k(
    const float* __restrict__ re, const float* __restrict__ Wd,
    const float* __restrict__ bd, float* __restrict__ out)
{
    const int b = blockIdx.x;
    const int t = threadIdx.x;
    float p0 = 0.f, p1 = 0.f;
    for (int d = t; d < 512; d += 64) {
        float r = re[b * 512 + d];
        p0 = fmaf(r, Wd[d], p0);
        p1 = fmaf(r, Wd[512 + d], p1);
    }
#pragma unroll
    for (int off = 32; off; off >>= 1) {
        p0 += __shfl_xor(p0, off);
        p1 += __shfl_xor(p1, off);
    }
    if (t == 0) {
        float l0 = p0 + bd[0], l1 = p1 + bd[1];
        float m = fmaxf(l0, l1);
        float lse = m + logf(expf(l0 - m) + expf(l1 - m));
        out[b * 2 + 0] = l0 - lse;
        out[b * 2 + 1] = l1 - lse;
    }
}

// ---------------------------------------------------------------------------
extern "C" void kernel_launch(void* const* d_in, const int* in_sizes, int n_in,
                              void* d_out, int out_size, void* d_ws, size_t ws_size,
                              hipStream_t stream)
{
    const float* A    = (const float*)d_in[0];
    const float* emb  = (const float*)d_in[1];
    const float* Wc   = (const float*)d_in[2];
    const float* bc   = (const float*)d_in[3];
    const float* W1   = (const float*)d_in[4];
    const float* b1   = (const float*)d_in[5];
    const float* W2   = (const float*)d_in[6];
    const float* b2   = (const float*)d_in[7];
    const float* Wd   = (const float*)d_in[8];
    const float* bd   = (const float*)d_in[9];
    const int* q_idx  = (const int*)d_in[10];
    const int* a_idx  = (const int*)d_in[11];
    float* out = (float*)d_out;
    float* ws  = (float*)d_ws;

    // workspace layout (floats)
    const long SZ_L1 = (long)NN * HH;           // 2,097,152
    float* layer1 = ws;                          // [8192,256]
    float* WcT    = layer1 + SZ_L1;              // [256,256]
    float* Qm     = WcT + 256 * 256;             // [8192,256]
    float* Am     = Qm + SZ_L1;                  // [8192,256]
    float* s      = Am + SZ_L1;                  // [64,128,128]
    float* eq     = s + (long)BB * LL * LL;      // [8192,256]
    float* ea     = eq + SZ_L1;                  // [8192,256]
    float* t_q    = ea + SZ_L1;                  // [8192,512]
    float* t_a    = t_q + (long)BB * LL * 512;   // [8192,512]
    float* Wcat   = t_a + (long)BB * LL * 512;   // [512,384]
    float* u_q    = Wcat + 512 * 384;            // [8192,384]
    float* u_a    = u_q + (long)BB * LL * 384;   // [8192,384]
    float* re     = u_a + (long)BB * LL * 384;   // [64,512]

    // 1. pack weights
    pack_w<<<768, 256, 0, stream>>>(Wc, WcT, W1, W2, Wcat);

    // 2. layer1 = A @ emb   (M=8192, N=256, K=8192)
    gemm_f32<0,0,0><<<dim3(HH / 64, NN / 64), 256, 0, stream>>>(
        A, emb, layer1, nullptr, nullptr, NN, HH, NN);

    // 3. gram: Qm/Am = relu(gather(layer1, idx) @ WcT + bc)
    gemm_f32<1,1,1><<<dim3(HH / 64, (BB * LL) / 64), 256, 0, stream>>>(
        layer1, WcT, Qm, bc, q_idx, BB * LL, HH, HH);
    gemm_f32<1,1,1><<<dim3(HH / 64, (BB * LL) / 64), 256, 0, stream>>>(
        layer1, WcT, Am, bc, a_idx, BB * LL, HH, HH);

    // 4. attention
    attn_q<<<BB * LL, 128, 0, stream>>>(Qm, Am, s, eq);
    attn_a<<<BB * LL, 128, 0, stream>>>(Qm, s, ea);

    // 5. t features
    build_t<<<(BB * LL * HH) / 256, 256, 0, stream>>>(Qm, eq, t_q);
    build_t<<<(BB * LL * HH) / 256, 256, 0, stream>>>(Am, ea, t_a);

    // 6. encoder GEMMs: u = t @ Wcat  (M=8192, N=384, K=512)
    gemm_f32<0,0,0><<<dim3(384 / 64, (BB * LL) / 64), 256, 0, stream>>>(
        t_q, Wcat, u_q, nullptr, nullptr, BB * LL, 384, 512);
    gemm_f32<0,0,0><<<dim3(384 / 64, (BB * LL) / 64), 256, 0, stream>>>(
        t_a, Wcat, u_a, nullptr, nullptr, BB * LL, 384, 512);

    // 7. pool + final
    pool_re<<<BB, 256, 0, stream>>>(u_q, u_a, b1, b2, re);
    final_k<<<BB, 64, 0, stream>>>(re, Wd, bd, out);
}

// Round 2
// 604.906 us; speedup vs baseline: 1.6372x; 1.6372x over previous
//
#include <hip/hip_runtime.h>
#include <hip/hip_bf16.h>
#include <math.h>

// Problem constants
#define NN 8192
#define HH 256
#define KK 128
#define BB 64
#define LL 128

typedef __attribute__((ext_vector_type(8))) short short8v;   // 8 bf16 (4 VGPRs)
typedef __attribute__((ext_vector_type(4))) float f32x4;     // MFMA accumulator

static __device__ inline short bf16bits(float f) {
    __hip_bfloat16 h = __float2bfloat16(f);
    return __builtin_bit_cast(short, h);
}

static __device__ inline short8v cvt8(float4 f0, float4 f1) {
    short8v r;
    r[0] = bf16bits(f0.x); r[1] = bf16bits(f0.y);
    r[2] = bf16bits(f0.z); r[3] = bf16bits(f0.w);
    r[4] = bf16bits(f1.x); r[5] = bf16bits(f1.y);
    r[6] = bf16bits(f1.z); r[7] = bf16bits(f1.w);
    return r;
}

// ---------------------------------------------------------------------------
// emb [8192][256] f32  ->  embT [256][8192] bf16 bits
// ---------------------------------------------------------------------------
__global__ __launch_bounds__(256) void transpose_emb(
    const float* __restrict__ emb, short* __restrict__ embT)
{
    __shared__ short tile[64][65];
    const int k0 = blockIdx.x * 64;   // grid.x = 128
    const int h0 = blockIdx.y * 64;   // grid.y = 4
    const int t = threadIdx.x;
#pragma unroll
    for (int i = 0; i < 16; i++) {
        int idx = t + i * 256;            // 0..4095
        int k = idx >> 6, h = idx & 63;   // read coalesced over h
        tile[h][k] = bf16bits(emb[(long)(k0 + k) * 256 + h0 + h]);
    }
    __syncthreads();
#pragma unroll
    for (int i = 0; i < 16; i++) {
        int idx = t + i * 256;
        int h = idx >> 6, k = idx & 63;   // write coalesced over k
        embT[(long)(h0 + h) * NN + k0 + k] = tile[h][k];
    }
}

// ---------------------------------------------------------------------------
// layer1 partials: Part[sk][m][n] = sum_{k in chunk sk} A[m][k]*emb[k][n]
// bf16 MFMA 16x16x32, fused fp32->bf16 convert of A, no LDS.
// Block: 256 threads = 4 waves, each wave owns a 64-col quadrant of BN=256.
// BM=64, split-K x4 -> grid (128, 4) = 512 blocks.
// ---------------------------------------------------------------------------
#define SPLITK 4
__global__ __launch_bounds__(256) void layer1_mfma(
    const float* __restrict__ A, const short* __restrict__ embT,
    float* __restrict__ Part)
{
    const int m0 = blockIdx.x * 64;
    const int sk = blockIdx.y;
    const int KS = NN / SPLITK;           // 2048
    const int k_begin = sk * KS;
    const int wave = threadIdx.x >> 6;    // n-quadrant 0..3
    const int lane = threadIdx.x & 63;
    const int n0 = wave * 64;
    const int r16 = lane & 15;            // fragment row (A) / col (B)
    const int kg = lane >> 4;             // k-group 0..3

    f32x4 acc[4][4] = {};                 // [m-frag][n-frag]

    const float* Abase = A + (long)(m0 + r16) * NN + k_begin + kg * 8;
    const short* Bbase = embT + (long)(n0 + r16) * NN + k_begin + kg * 8;

    for (int ks = 0; ks < KS; ks += 32) {
        short8v a[4], b[4];
#pragma unroll
        for (int i = 0; i < 4; i++) {
            const float* ap = Abase + (long)i * 16 * NN + ks;
            float4 f0 = *(const float4*)ap;
            float4 f1 = *(const float4*)(ap + 4);
            a[i] = cvt8(f0, f1);
            b[i] = *(const short8v*)(Bbase + (long)i * 16 * NN + ks);
        }
#pragma unroll
        for (int i = 0; i < 4; i++)
#pragma unroll
            for (int j = 0; j < 4; j++)
                acc[i][j] = __builtin_amdgcn_mfma_f32_16x16x32_bf16(
                    a[i], b[j], acc[i][j], 0, 0, 0);
    }

    // D layout: col = lane&15, row = (lane>>4)*4 + reg  (per 16x16 fragment)
    float* P = Part + (long)sk * NN * HH;
#pragma unroll
    for (int i = 0; i < 4; i++) {
#pragma unroll
        for (int j = 0; j < 4; j++) {
#pragma unroll
            for (int r = 0; r < 4; r++) {
                int row = m0 + i * 16 + kg * 4 + r;
                int col = n0 + j * 16 + r16;
                P[(long)row * HH + col] = acc[i][j][r];
            }
        }
    }
}

// layer1 = sum of 4 partials
__global__ __launch_bounds__(256) void reduce4(
    const float* __restrict__ P, float* __restrict__ out)
{
    const long n4 = (long)NN * HH / 4;    // float4 count
    long i = blockIdx.x * 256 + threadIdx.x;
    if (i >= n4) return;
    const float4* p = (const float4*)P;
    float4 a = p[i], b = p[i + n4], c = p[i + 2 * n4], d = p[i + 3 * n4];
    float4 s;
    s.x = a.x + b.x + c.x + d.x;
    s.y = a.y + b.y + c.y + d.y;
    s.z = a.z + b.z + c.z + d.z;
    s.w = a.w + b.w + c.w + d.w;
    ((float4*)out)[i] = s;
}

// ---------------------------------------------------------------------------
// Generic tiled fp32 GEMM (unchanged from R1) for the small GEMMs.
// ---------------------------------------------------------------------------
template<int RELU, int BIAS, int GATHER>
__global__ __launch_bounds__(256) void gemm_f32(
    const float* __restrict__ Ag, const float* __restrict__ Bg,
    float* __restrict__ Cg, const float* __restrict__ bias,
    const int* __restrict__ rowidx, int M, int N, int Kd)
{
    __shared__ __align__(16) float As[16][68];
    __shared__ __align__(16) float Bs[16][68];
    const int tid = threadIdx.x;
    const int tx = tid & 15, ty = tid >> 4;
    const int m0 = blockIdx.y * 64, n0 = blockIdx.x * 64;

    const int lk = tid & 15;
    const int lmb = tid >> 4;
    const int nb = tid & 63;
    const int kb = tid >> 6;

    long arow[4];
#pragma unroll
    for (int i = 0; i < 4; i++) {
        int m = m0 + lmb + i * 16;
        int r = GATHER ? rowidx[m] : m;
        arow[i] = (long)r * Kd;
    }

    float acc[4][4] = {};

    for (int k0 = 0; k0 < Kd; k0 += 16) {
#pragma unroll
        for (int i = 0; i < 4; i++)
            As[lk][lmb + i * 16] = Ag[arow[i] + k0 + lk];
#pragma unroll
        for (int i = 0; i < 4; i++)
            Bs[kb + i * 4][nb] = Bg[(long)(k0 + kb + i * 4) * N + n0 + nb];
        __syncthreads();
#pragma unroll
        for (int k = 0; k < 16; k++) {
            float4 av = *(const float4*)&As[k][ty * 4];
            float4 bv = *(const float4*)&Bs[k][tx * 4];
            float a0 = av.x, a1 = av.y, a2 = av.z, a3 = av.w;
            float b0 = bv.x, b1 = bv.y, b2 = bv.z, b3 = bv.w;
            acc[0][0] = fmaf(a0, b0, acc[0][0]); acc[0][1] = fmaf(a0, b1, acc[0][1]);
            acc[0][2] = fmaf(a0, b2, acc[0][2]); acc[0][3] = fmaf(a0, b3, acc[0][3]);
            acc[1][0] = fmaf(a1, b0, acc[1][0]); acc[1][1] = fmaf(a1, b1, acc[1][1]);
            acc[1][2] = fmaf(a1, b2, acc[1][2]); acc[1][3] = fmaf(a1, b3, acc[1][3]);
            acc[2][0] = fmaf(a2, b0, acc[2][0]); acc[2][1] = fmaf(a2, b1, acc[2][1]);
            acc[2][2] = fmaf(a2, b2, acc[2][2]); acc[2][3] = fmaf(a2, b3, acc[2][3]);
            acc[3][0] = fmaf(a3, b0, acc[3][0]); acc[3][1] = fmaf(a3, b1, acc[3][1]);
            acc[3][2] = fmaf(a3, b2, acc[3][2]); acc[3][3] = fmaf(a3, b3, acc[3][3]);
        }
        __syncthreads();
    }

#pragma unroll
    for (int i = 0; i < 4; i++) {
        int m = m0 + ty * 4 + i;
        float4 o;
        float v0 = acc[i][0], v1 = acc[i][1], v2 = acc[i][2], v3 = acc[i][3];
        int n = n0 + tx * 4;
        if (BIAS) { v0 += bias[n]; v1 += bias[n + 1]; v2 += bias[n + 2]; v3 += bias[n + 3]; }
        if (RELU) { v0 = fmaxf(v0, 0.f); v1 = fmaxf(v1, 0.f); v2 = fmaxf(v2, 0.f); v3 = fmaxf(v3, 0.f); }
        o.x = v0; o.y = v1; o.z = v2; o.w = v3;
        *(float4*)&Cg[(long)m * N + n] = o;
    }
}

// ---------------------------------------------------------------------------
__global__ void pack_w(const float* __restrict__ Wc, float* __restrict__ WcT,
                       const float* __restrict__ W1, const float* __restrict__ W2,
                       float* __restrict__ Wcat)
{
    int i = blockIdx.x * blockDim.x + threadIdx.x;
    if (i < 256 * 256) {
        int o = i / 256, h = i % 256;
        WcT[h * 256 + o] = Wc[i];
    }
    if (i < 512 * 384) {
        int d = i / 384, c = i % 384;
        int k = c & 127, g = c >> 7;
        float v = (g == 0) ? W1[k * 512 + d] : W2[k * 1024 + (g - 1) * 512 + d];
        Wcat[i] = v;
    }
}

// ---------------------------------------------------------------------------
__global__ __launch_bounds__(128) void attn_q(
    const float* __restrict__ Qm, const float* __restrict__ Am,
    float* __restrict__ s, float* __restrict__ eq)
{
    const int b = blockIdx.x >> 7, q = blockIdx.x & 127;
    const int t = threadIdx.x;
    __shared__ float qrow[256];
    __shared__ float p[128];
    __shared__ float red[2];

    const long qoff = ((long)b * 128 + q) * 256;
    qrow[t] = Qm[qoff + t];
    qrow[t + 128] = Qm[qoff + 128 + t];
    __syncthreads();

    const float4* arow4 = (const float4*)(Am + ((long)b * 128 + t) * 256);
    float acc = 0.f;
#pragma unroll 8
    for (int h4 = 0; h4 < 64; h4++) {
        float4 av = arow4[h4];
        acc += qrow[h4 * 4 + 0] * av.x + qrow[h4 * 4 + 1] * av.y +
               qrow[h4 * 4 + 2] * av.z + qrow[h4 * 4 + 3] * av.w;
    }
    s[((long)b * 128 + q) * 128 + t] = acc;

    float m = acc;
#pragma unroll
    for (int off = 32; off; off >>= 1) m = fmaxf(m, __shfl_xor(m, off));
    if ((t & 63) == 0) red[t >> 6] = m;
    __syncthreads();
    m = fmaxf(red[0], red[1]);
    float ex = expf(acc - m);
    float ssum = ex;
#pragma unroll
    for (int off = 32; off; off >>= 1) ssum += __shfl_xor(ssum, off);
    __syncthreads();
    if ((t & 63) == 0) red[t >> 6] = ssum;
    __syncthreads();
    ssum = red[0] + red[1];
    p[t] = ex / ssum;
    __syncthreads();

    float e0 = 0.f, e1 = 0.f;
    for (int k = 0; k < 128; k++) {
        float pv = p[k];
        const float* ar = Am + ((long)b * 128 + k) * 256;
        e0 = fmaf(pv, ar[t], e0);
        e1 = fmaf(pv, ar[t + 128], e1);
    }
    eq[qoff + t] = e0;
    eq[qoff + t + 128] = e1;
}

__global__ __launch_bounds__(128) void attn_a(
    const float* __restrict__ Qm, const float* __restrict__ s,
    float* __restrict__ ea)
{
    const int b = blockIdx.x >> 7, k = blockIdx.x & 127;
    const int t = threadIdx.x;
    __shared__ float p[128];
    __shared__ float red[2];

    float sv = s[((long)b * 128 + t) * 128 + k];
    float m = sv;
#pragma unroll
    for (int off = 32; off; off >>= 1) m = fmaxf(m, __shfl_xor(m, off));
    if ((t & 63) == 0) red[t >> 6] = m;
    __syncthreads();
    m = fmaxf(red[0], red[1]);
    float ex = expf(sv - m);
    float ssum = ex;
#pragma unroll
    for (int off = 32; off; off >>= 1) ssum += __shfl_xor(ssum, off);
    __syncthreads();
    if ((t & 63) == 0) red[t >> 6] = ssum;
    __syncthreads();
    ssum = red[0] + red[1];
    p[t] = ex / ssum;
    __syncthreads();

    float e0 = 0.f, e1 = 0.f;
    for (int q = 0; q < 128; q++) {
        float pv = p[q];
        const float* qr = Qm + ((long)b * 128 + q) * 256;
        e0 = fmaf(pv, qr[t], e0);
        e1 = fmaf(pv, qr[t + 128], e1);
    }
    const long aoff = ((long)b * 128 + k) * 256;
    ea[aoff + t] = e0;
    ea[aoff + t + 128] = e1;
}

// ---------------------------------------------------------------------------
__global__ void build_t(const float* __restrict__ X, const float* __restrict__ E,
                        float* __restrict__ t)
{
    int i = blockIdx.x * blockDim.x + threadIdx.x;   // over B*L*H
    if (i >= BB * LL * HH) return;
    int h = i & 255;
    int bl = i >> 8;
    float x = X[i], e = E[i];
    float d = x - e;
    t[(long)bl * 512 + h] = d * d;
    t[(long)bl * 512 + 256 + h] = x * e;
}

// ---------------------------------------------------------------------------
__global__ __launch_bounds__(256) void pool_re(
    const float* __restrict__ u_q, const float* __restrict__ u_a,
    const float* __restrict__ b1, const float* __restrict__ b2,
    float* __restrict__ re)
{
    const int b = blockIdx.x;
    const int t = threadIdx.x;
#pragma unroll
    for (int side = 0; side < 2; side++) {
        const float* uu = side ? u_a : u_q;
        if (t < 128) {
            int k = t;
            float bias = b1[k];
            float mx = -1e30f;
            for (int l = 0; l < 128; l++) {
                float v = uu[((long)b * 128 + l) * 384 + k] + bias;
                mx = fmaxf(mx, v);
            }
            mx = fmaxf(mx, 0.f);
            re[b * 512 + side * 256 + k] = mx;
        } else {
            int k = t - 128;
            float bias = b2[k];
            float mx = -1e30f;
            for (int l = 0; l < 127; l++) {
                float v = uu[((long)b * 128 + l) * 384 + 128 + k]
                        + uu[((long)b * 128 + l + 1) * 384 + 256 + k] + bias;
                mx = fmaxf(mx, v);
            }
            mx = fmaxf(mx, 0.f);
            re[b * 512 + side * 256 + 128 + k] = mx;
        }
    }
}

// ---------------------------------------------------------------------------
__global__ __launch_bounds__(64) void final_k(
    const float* __restrict__ re, const float* __restrict__ Wd,
    const float* __restrict__ bd, float* __restrict__ out)
{
    const int b = blockIdx.x;
    const int t = threadIdx.x;
    float p0 = 0.f, p1 = 0.f;
    for (int d = t; d < 512; d += 64) {
        float r = re[b * 512 + d];
        p0 = fmaf(r, Wd[d], p0);
        p1 = fmaf(r, Wd[512 + d], p1);
    }
#pragma unroll
    for (int off = 32; off; off >>= 1) {
        p0 += __shfl_xor(p0, off);
        p1 += __shfl_xor(p1, off);
    }
    if (t == 0) {
        float l0 = p0 + bd[0], l1 = p1 + bd[1];
        float m = fmaxf(l0, l1);
        float lse = m + logf(expf(l0 - m) + expf(l1 - m));
        out[b * 2 + 0] = l0 - lse;
        out[b * 2 + 1] = l1 - lse;
    }
}

// ---------------------------------------------------------------------------
extern "C" void kernel_launch(void* const* d_in, const int* in_sizes, int n_in,
                              void* d_out, int out_size, void* d_ws, size_t ws_size,
                              hipStream_t stream)
{
    const float* A    = (const float*)d_in[0];
    const float* emb  = (const float*)d_in[1];
    const float* Wc   = (const float*)d_in[2];
    const float* bc   = (const float*)d_in[3];
    const float* W1   = (const float*)d_in[4];
    const float* b1   = (const float*)d_in[5];
    const float* W2   = (const float*)d_in[6];
    const float* b2   = (const float*)d_in[7];
    const float* Wd   = (const float*)d_in[8];
    const float* bd   = (const float*)d_in[9];
    const int* q_idx  = (const int*)d_in[10];
    const int* a_idx  = (const int*)d_in[11];
    float* out = (float*)d_out;
    float* ws  = (float*)d_ws;

    // workspace layout (floats)
    const long SZ_L1 = (long)NN * HH;           // 2,097,152
    float* layer1 = ws;                          // [8192,256]
    float* WcT    = layer1 + SZ_L1;              // [256,256]
    float* Qm     = WcT + 256 * 256;             // [8192,256]
    float* Am     = Qm + SZ_L1;                  // [8192,256]
    float* s      = Am + SZ_L1;                  // [64,128,128]
    float* eq     = s + (long)BB * LL * LL;      // [8192,256]
    float* ea     = eq + SZ_L1;                  // [8192,256]
    float* t_q    = ea + SZ_L1;                  // [8192,512]
    float* t_a    = t_q + (long)BB * LL * 512;   // [8192,512]
    float* Wcat   = t_a + (long)BB * LL * 512;   // [512,384]
    float* u_q    = Wcat + 512 * 384;            // [8192,384]
    float* u_a    = u_q + (long)BB * LL * 384;   // [8192,384]
    float* re     = u_a + (long)BB * LL * 384;   // [64,512]

    // Aliased scratch (used only BEFORE t_q/u_q are produced):
    float* Part  = t_q;                // [4][8192][256] fp32 = 32 MB (t_q+t_a)
    short* embT  = (short*)u_q;        // [256][8192] bf16 = 4 MB

    // 1. pack weights + transpose emb to bf16
    pack_w<<<768, 256, 0, stream>>>(Wc, WcT, W1, W2, Wcat);
    transpose_emb<<<dim3(128, 4), 256, 0, stream>>>(emb, embT);

    // 2. layer1 = A @ emb via bf16 MFMA, split-K x4 + reduce
    layer1_mfma<<<dim3(NN / 64, SPLITK), 256, 0, stream>>>(A, embT, Part);
    reduce4<<<(int)((long)NN * HH / 4 / 256), 256, 0, stream>>>(Part, layer1);

    // 3. gram: Qm/Am = relu(gather(layer1, idx) @ WcT + bc)
    gemm_f32<1,1,1><<<dim3(HH / 64, (BB * LL) / 64), 256, 0, stream>>>(
        layer1, WcT, Qm, bc, q_idx, BB * LL, HH, HH);
    gemm_f32<1,1,1><<<dim3(HH / 64, (BB * LL) / 64), 256, 0, stream>>>(
        layer1, WcT, Am, bc, a_idx, BB * LL, HH, HH);

    // 4. attention
    attn_q<<<BB * LL, 128, 0, stream>>>(Qm, Am, s, eq);
    attn_a<<<BB * LL, 128, 0, stream>>>(Qm, s, ea);

    // 5. t features
    build_t<<<(BB * LL * HH) / 256, 256, 0, stream>>>(Qm, eq, t_q);
    build_t<<<(BB * LL * HH) / 256, 256, 0, stream>>>(Am, ea, t_a);

    // 6. encoder GEMMs: u = t @ Wcat  (M=8192, N=384, K=512)
    gemm_f32<0,0,0><<<dim3(384 / 64, (BB * LL) / 64), 256, 0, stream>>>(
        t_q, Wcat, u_q, nullptr, nullptr, BB * LL, 384, 512);
    gemm_f32<0,0,0><<<dim3(384 / 64, (BB * LL) / 64), 256, 0, stream>>>(
        t_a, Wcat, u_a, nullptr, nullptr, BB * LL, 384, 512);

    // 7. pool + final
    pool_re<<<BB, 256, 0, stream>>>(u_q, u_a, b1, b2, re);
    final_k<<<BB, 64, 0, stream>>>(re, Wd, bd, out);
}

// Round 3
// 445.651 us; speedup vs baseline: 2.2223x; 1.3574x over previous
//
#include <hip/hip_runtime.h>
#include <hip/hip_bf16.h>
#include <math.h>

// Problem constants
#define NN 8192
#define HH 256
#define KK 128
#define BB 64
#define LL 128

#define SPLITK 8

typedef __attribute__((ext_vector_type(8))) short short8v;   // 8 bf16 (4 VGPRs)
typedef __attribute__((ext_vector_type(4))) float f32x4;     // MFMA accumulator

static __device__ inline short bf16bits(float f) {
    __hip_bfloat16 h = __float2bfloat16(f);
    return __builtin_bit_cast(short, h);
}

static __device__ inline short8v cvt8(float4 f0, float4 f1) {
    short8v r;
    r[0] = bf16bits(f0.x); r[1] = bf16bits(f0.y);
    r[2] = bf16bits(f0.z); r[3] = bf16bits(f0.w);
    r[4] = bf16bits(f1.x); r[5] = bf16bits(f1.y);
    r[6] = bf16bits(f1.z); r[7] = bf16bits(f1.w);
    return r;
}

// async global(bf16) -> LDS, 16 bytes per lane, linear dest
static __device__ inline void glds16(const short* src, short* lds) {
    __builtin_amdgcn_global_load_lds(
        (const __attribute__((address_space(1))) void*)src,
        (__attribute__((address_space(3))) void*)lds, 16, 0, 0);
}

// ---------------------------------------------------------------------------
// emb [8192][256] f32  ->  embT [256][8192] bf16 bits  (B^T for layer1)
// ---------------------------------------------------------------------------
__global__ __launch_bounds__(256) void transpose_emb(
    const float* __restrict__ emb, short* __restrict__ embT)
{
    __shared__ short tile[64][65];
    const int k0 = blockIdx.x * 64;   // grid.x = 128
    const int h0 = blockIdx.y * 64;   // grid.y = 4
    const int t = threadIdx.x;
#pragma unroll
    for (int i = 0; i < 16; i++) {
        int idx = t + i * 256;
        int k = idx >> 6, h = idx & 63;
        tile[h][k] = bf16bits(emb[(long)(k0 + k) * 256 + h0 + h]);
    }
    __syncthreads();
#pragma unroll
    for (int i = 0; i < 16; i++) {
        int idx = t + i * 256;
        int h = idx >> 6, k = idx & 63;
        embT[(long)(h0 + h) * NN + k0 + k] = tile[h][k];
    }
}

// ---------------------------------------------------------------------------
// Unified bf16-MFMA GEMM.
//   A: fp32 [M][Kd] (optionally row-gathered), converted to bf16 in-flight
//   B: bf16 [N][Kd]  (B^T layout, 8 consecutive k per fragment load)
//   C: fp32 [M][N]   (or Part[sk][M][N] when SK>1)
// Tile: BM x (4*NW), BK=32. Block = BM*4 threads = BM/16 waves (2D wave grid:
// (BM/64) m-rows x 4 n-cols, each wave 64 x NW). LDS double-buffered,
// one barrier per K-step, B staged via global_load_lds, A reg-staged + cvt.
// ---------------------------------------------------------------------------
template<int BM, int NW, int SK, int GATHER, int BIAS, int RELU>
__global__ __launch_bounds__(BM * 4) void gemm_mfma(
    const float* __restrict__ Ag, const short* __restrict__ Bt,
    float* __restrict__ Cg, const float* __restrict__ bias,
    const int* __restrict__ rowidx, int M, int N, int Kd)
{
    constexpr int BN = 4 * NW;
    constexpr int NB = NW / 16;          // n-frags per wave
    constexpr int NTHR = BM * 4;
    constexpr int BCALLS = (4 * NW) / BM; // gload_lds calls per B tile

    __shared__ short As[2][BM * 32];
    __shared__ short Bs[2][BN * 32];

    const int tid = threadIdx.x;
    const int wave = tid >> 6, lane = tid & 63;
    const int wr = wave >> 2;            // m-row of wave (0..BM/64-1)
    const int wc = wave & 3;             // n-col of wave (0..3)
    const int r16 = lane & 15;
    const int kg = lane >> 4;            // k-octet 0..3

    const int m0 = blockIdx.x * BM;
    const int KS = Kd / SK;
    const int kbeg = blockIdx.y * KS;
    const int niter = KS / 32;

    // A staging: chunk = tid -> row = tid>>2 (0..BM-1), kc = (tid&3)*8
    const int arow = tid >> 2;
    const int akc = (tid & 3) * 8;
    long arow_g;
    {
        int r = GATHER ? rowidx[m0 + arow] : (m0 + arow);
        arow_g = (long)r * Kd;
    }
    const float* Abase = Ag + arow_g + kbeg + akc;
    short* aslot0 = &As[0][arow * 32 + akc];
    short* aslot1 = &As[1][arow * 32 + akc];

    f32x4 acc[4][NB] = {};

    // ---- prologue: stage tile 0 into buffer 0
    {
        float4 f0 = *(const float4*)(Abase);
        float4 f1 = *(const float4*)(Abase + 4);
#pragma unroll
        for (int c = 0; c < BCALLS; c++) {
            int chunk = c * NTHR + tid;
            int n = chunk >> 2, kc = (chunk & 3) * 8;
            glds16(Bt + (long)n * Kd + kbeg + kc,
                   &Bs[0][(c * NTHR + wave * 64) * 8]);
        }
        *(short8v*)aslot0 = cvt8(f0, f1);
    }
    __syncthreads();

    int cur = 0;
    for (int t = 0; t < niter; t++) {
        const int nxt = cur ^ 1;
        const bool more = (t + 1 < niter);
        float4 f0, f1;
        if (more) {
            const float* ap = Abase + (t + 1) * 32;
            f0 = *(const float4*)ap;
            f1 = *(const float4*)(ap + 4);
            const int kt = kbeg + (t + 1) * 32;
#pragma unroll
            for (int c = 0; c < BCALLS; c++) {
                int chunk = c * NTHR + tid;
                int n = chunk >> 2, kc = (chunk & 3) * 8;
                glds16(Bt + (long)n * Kd + kt + kc,
                       &Bs[nxt][(c * NTHR + wave * 64) * 8]);
            }
        }

        // compute on cur
        short8v a[4], b[NB];
#pragma unroll
        for (int i = 0; i < 4; i++)
            a[i] = *(const short8v*)&As[cur][(wr * 64 + i * 16 + r16) * 32 + kg * 8];
#pragma unroll
        for (int j = 0; j < NB; j++)
            b[j] = *(const short8v*)&Bs[cur][(wc * NW + j * 16 + r16) * 32 + kg * 8];
#pragma unroll
        for (int i = 0; i < 4; i++)
#pragma unroll
            for (int j = 0; j < NB; j++)
                acc[i][j] = __builtin_amdgcn_mfma_f32_16x16x32_bf16(
                    a[i], b[j], acc[i][j], 0, 0, 0);

        if (more)
            *(short8v*)(nxt ? aslot1 : aslot0) = cvt8(f0, f1);

        __syncthreads();
        cur = nxt;
    }

    // ---- epilogue
    float* Cp = Cg + (SK > 1 ? (long)blockIdx.y * M * N : 0);
#pragma unroll
    for (int i = 0; i < 4; i++) {
#pragma unroll
        for (int j = 0; j < NB; j++) {
            int col = wc * NW + j * 16 + r16;
            float bv = BIAS ? bias[col] : 0.f;
#pragma unroll
            for (int r = 0; r < 4; r++) {
                int row = m0 + wr * 64 + i * 16 + kg * 4 + r;
                float v = acc[i][j][r] + bv;
                if (RELU) v = fmaxf(v, 0.f);
                Cp[(long)row * N + col] = v;
            }
        }
    }
}

// layer1 = sum of SPLITK partials
__global__ __launch_bounds__(256) void reduceK(
    const float* __restrict__ P, float* __restrict__ out)
{
    const long n4 = (long)NN * HH / 4;
    long i = (long)blockIdx.x * 256 + threadIdx.x;
    if (i >= n4) return;
    const float4* p = (const float4*)P;
    float4 s = p[i];
#pragma unroll
    for (int k = 1; k < SPLITK; k++) {
        float4 v = p[i + (long)k * n4];
        s.x += v.x; s.y += v.y; s.z += v.z; s.w += v.w;
    }
    ((float4*)out)[i] = s;
}

// ---------------------------------------------------------------------------
// Pack weights to bf16 B^T layouts.
//  Wcb [256][256] = Wc (already [out][in])
//  WcatT [384][512]: n<128 -> W1[n][:]; 128..255 -> W2[n-128][0][:];
//                    256..383 -> W2[n-256][1][:]
// ---------------------------------------------------------------------------
__global__ void pack_w(const float* __restrict__ Wc, short* __restrict__ Wcb,
                       const float* __restrict__ W1, const float* __restrict__ W2,
                       short* __restrict__ WcatT)
{
    int i = blockIdx.x * blockDim.x + threadIdx.x;
    if (i < 256 * 256) Wcb[i] = bf16bits(Wc[i]);
    if (i < 384 * 512) {
        int n = i >> 9, d = i & 511;
        float v;
        if (n < 128)      v = W1[n * 512 + d];
        else if (n < 256) v = W2[(n - 128) * 1024 + d];
        else              v = W2[(n - 256) * 1024 + 512 + d];
        WcatT[i] = bf16bits(v);
    }
}

// ---------------------------------------------------------------------------
__global__ __launch_bounds__(128) void attn_q(
    const float* __restrict__ Qm, const float* __restrict__ Am,
    float* __restrict__ s, float* __restrict__ eq)
{
    const int b = blockIdx.x >> 7, q = blockIdx.x & 127;
    const int t = threadIdx.x;
    __shared__ float qrow[256];
    __shared__ float p[128];
    __shared__ float red[2];

    const long qoff = ((long)b * 128 + q) * 256;
    qrow[t] = Qm[qoff + t];
    qrow[t + 128] = Qm[qoff + 128 + t];
    __syncthreads();

    const float4* arow4 = (const float4*)(Am + ((long)b * 128 + t) * 256);
    float acc = 0.f;
#pragma unroll 8
    for (int h4 = 0; h4 < 64; h4++) {
        float4 av = arow4[h4];
        acc += qrow[h4 * 4 + 0] * av.x + qrow[h4 * 4 + 1] * av.y +
               qrow[h4 * 4 + 2] * av.z + qrow[h4 * 4 + 3] * av.w;
    }
    s[((long)b * 128 + q) * 128 + t] = acc;

    float m = acc;
#pragma unroll
    for (int off = 32; off; off >>= 1) m = fmaxf(m, __shfl_xor(m, off));
    if ((t & 63) == 0) red[t >> 6] = m;
    __syncthreads();
    m = fmaxf(red[0], red[1]);
    float ex = expf(acc - m);
    float ssum = ex;
#pragma unroll
    for (int off = 32; off; off >>= 1) ssum += __shfl_xor(ssum, off);
    __syncthreads();
    if ((t & 63) == 0) red[t >> 6] = ssum;
    __syncthreads();
    ssum = red[0] + red[1];
    p[t] = ex / ssum;
    __syncthreads();

    float e0 = 0.f, e1 = 0.f;
    for (int k = 0; k < 128; k++) {
        float pv = p[k];
        const float* ar = Am + ((long)b * 128 + k) * 256;
        e0 = fmaf(pv, ar[t], e0);
        e1 = fmaf(pv, ar[t + 128], e1);
    }
    eq[qoff + t] = e0;
    eq[qoff + t + 128] = e1;
}

__global__ __launch_bounds__(128) void attn_a(
    const float* __restrict__ Qm, const float* __restrict__ s,
    float* __restrict__ ea)
{
    const int b = blockIdx.x >> 7, k = blockIdx.x & 127;
    const int t = threadIdx.x;
    __shared__ float p[128];
    __shared__ float red[2];

    float sv = s[((long)b * 128 + t) * 128 + k];
    float m = sv;
#pragma unroll
    for (int off = 32; off; off >>= 1) m = fmaxf(m, __shfl_xor(m, off));
    if ((t & 63) == 0) red[t >> 6] = m;
    __syncthreads();
    m = fmaxf(red[0], red[1]);
    float ex = expf(sv - m);
    float ssum = ex;
#pragma unroll
    for (int off = 32; off; off >>= 1) ssum += __shfl_xor(ssum, off);
    __syncthreads();
    if ((t & 63) == 0) red[t >> 6] = ssum;
    __syncthreads();
    ssum = red[0] + red[1];
    p[t] = ex / ssum;
    __syncthreads();

    float e0 = 0.f, e1 = 0.f;
    for (int q = 0; q < 128; q++) {
        float pv = p[q];
        const float* qr = Qm + ((long)b * 128 + q) * 256;
        e0 = fmaf(pv, qr[t], e0);
        e1 = fmaf(pv, qr[t + 128], e1);
    }
    const long aoff = ((long)b * 128 + k) * 256;
    ea[aoff + t] = e0;
    ea[aoff + t + 128] = e1;
}

// ---------------------------------------------------------------------------
__global__ void build_t(const float* __restrict__ X, const float* __restrict__ E,
                        float* __restrict__ t)
{
    int i = blockIdx.x * blockDim.x + threadIdx.x;
    if (i >= BB * LL * HH) return;
    int h = i & 255;
    int bl = i >> 8;
    float x = X[i], e = E[i];
    float d = x - e;
    t[(long)bl * 512 + h] = d * d;
    t[(long)bl * 512 + 256 + h] = x * e;
}

// ---------------------------------------------------------------------------
__global__ __launch_bounds__(256) void pool_re(
    const float* __restrict__ u_q, const float* __restrict__ u_a,
    const float* __restrict__ b1, const float* __restrict__ b2,
    float* __restrict__ re)
{
    const int b = blockIdx.x;
    const int t = threadIdx.x;
#pragma unroll
    for (int side = 0; side < 2; side++) {
        const float* uu = side ? u_a : u_q;
        if (t < 128) {
            int k = t;
            float bias = b1[k];
            float mx = -1e30f;
            for (int l = 0; l < 128; l++) {
                float v = uu[((long)b * 128 + l) * 384 + k] + bias;
                mx = fmaxf(mx, v);
            }
            mx = fmaxf(mx, 0.f);
            re[b * 512 + side * 256 + k] = mx;
        } else {
            int k = t - 128;
            float bias = b2[k];
            float mx = -1e30f;
            for (int l = 0; l < 127; l++) {
                float v = uu[((long)b * 128 + l) * 384 + 128 + k]
                        + uu[((long)b * 128 + l + 1) * 384 + 256 + k] + bias;
                mx = fmaxf(mx, v);
            }
            mx = fmaxf(mx, 0.f);
            re[b * 512 + side * 256 + 128 + k] = mx;
        }
    }
}

// ---------------------------------------------------------------------------
__global__ __launch_bounds__(64) void final_k(
    const float* __restrict__ re, const float* __restrict__ Wd,
    const float* __restrict__ bd, float* __restrict__ out)
{
    const int b = blockIdx.x;
    const int t = threadIdx.x;
    float p0 = 0.f, p1 = 0.f;
    for (int d = t; d < 512; d += 64) {
        float r = re[b * 512 + d];
        p0 = fmaf(r, Wd[d], p0);
        p1 = fmaf(r, Wd[512 + d], p1);
    }
#pragma unroll
    for (int off = 32; off; off >>= 1) {
        p0 += __shfl_xor(p0, off);
        p1 += __shfl_xor(p1, off);
    }
    if (t == 0) {
        float l0 = p0 + bd[0], l1 = p1 + bd[1];
        float m = fmaxf(l0, l1);
        float lse = m + logf(expf(l0 - m) + expf(l1 - m));
        out[b * 2 + 0] = l0 - lse;
        out[b * 2 + 1] = l1 - lse;
    }
}

// ---------------------------------------------------------------------------
extern "C" void kernel_launch(void* const* d_in, const int* in_sizes, int n_in,
                              void* d_out, int out_size, void* d_ws, size_t ws_size,
                              hipStream_t stream)
{
    const float* A    = (const float*)d_in[0];
    const float* emb  = (const float*)d_in[1];
    const float* Wc   = (const float*)d_in[2];
    const float* bc   = (const float*)d_in[3];
    const float* W1   = (const float*)d_in[4];
    const float* b1   = (const float*)d_in[5];
    const float* W2   = (const float*)d_in[6];
    const float* b2   = (const float*)d_in[7];
    const float* Wd   = (const float*)d_in[8];
    const float* bd   = (const float*)d_in[9];
    const int* q_idx  = (const int*)d_in[10];
    const int* a_idx  = (const int*)d_in[11];
    float* out = (float*)d_out;
    float* ws  = (float*)d_ws;

    // workspace layout (floats)
    const long SZ_L1 = (long)NN * HH;            // 2,097,152
    float* layer1 = ws;                          // [8192,256] f32
    float* Wcb_f  = layer1 + SZ_L1;              // slot 65536 f (bf16 256x256)
    float* Wcat_f = Wcb_f + 65536;               // slot 98304 f (bf16 384x512)
    float* Qm     = Wcat_f + 98304;              // [8192,256]
    float* Am     = Qm + SZ_L1;                  // [8192,256]
    float* s      = Am + SZ_L1;                  // [64,128,128]   (1M)
    float* eq     = s + (long)BB * LL * LL;      // [8192,256]     (2M)
    float* ea     = eq + SZ_L1;                  // [8192,256]     (2M)
    float* t_q    = ea + SZ_L1;                  // [8192,512]     (4M)
    float* t_a    = t_q + (long)BB * LL * 512;   // [8192,512]     (4M)
    float* u_q    = t_a + (long)BB * LL * 512;   // [8192,384]     (3M)
    float* u_a    = u_q + (long)BB * LL * 384;   // [8192,384]     (3M)
    float* re     = u_a + (long)BB * LL * 384;   // [64,512]

    short* Wcb   = (short*)Wcb_f;
    short* WcatT = (short*)Wcat_f;
    // Aliased scratch, dead before consumers write their slots:
    float* Part  = s;                  // [8][8192][256] = 16M f = s..u_q span
    short* embT  = (short*)u_a;        // [256][8192] bf16 = 1M f slot

    // 1. pack weights + transpose emb to bf16
    pack_w<<<768, 256, 0, stream>>>(Wc, Wcb, W1, W2, WcatT);
    transpose_emb<<<dim3(128, 4), 256, 0, stream>>>(emb, embT);

    // 2. layer1 = A @ emb : BM=128, BN=256, splitK=8 -> 512 blocks
    gemm_mfma<128, 64, SPLITK, 0, 0, 0><<<dim3(NN / 128, SPLITK), 512, 0, stream>>>(
        A, embT, Part, nullptr, nullptr, NN, HH, NN);
    reduceK<<<(int)(SZ_L1 / 4 / 256), 256, 0, stream>>>(Part, layer1);

    // 3. gram: Qm/Am = relu(gather(layer1, idx) @ Wc^T + bc)
    gemm_mfma<64, 64, 1, 1, 1, 1><<<dim3((BB * LL) / 64, 1), 256, 0, stream>>>(
        layer1, Wcb, Qm, bc, q_idx, BB * LL, HH, HH);
    gemm_mfma<64, 64, 1, 1, 1, 1><<<dim3((BB * LL) / 64, 1), 256, 0, stream>>>(
        layer1, Wcb, Am, bc, a_idx, BB * LL, HH, HH);

    // 4. attention
    attn_q<<<BB * LL, 128, 0, stream>>>(Qm, Am, s, eq);
    attn_a<<<BB * LL, 128, 0, stream>>>(Qm, s, ea);

    // 5. t features
    build_t<<<(BB * LL * HH) / 256, 256, 0, stream>>>(Qm, eq, t_q);
    build_t<<<(BB * LL * HH) / 256, 256, 0, stream>>>(Am, ea, t_a);

    // 6. encoder GEMMs: u = t @ Wcat (M=8192, N=384, K=512), bias added in pool
    gemm_mfma<64, 96, 1, 0, 0, 0><<<dim3((BB * LL) / 64, 1), 256, 0, stream>>>(
        t_q, WcatT, u_q, nullptr, nullptr, BB * LL, 384, 512);
    gemm_mfma<64, 96, 1, 0, 0, 0><<<dim3((BB * LL) / 64, 1), 256, 0, stream>>>(
        t_a, WcatT, u_a, nullptr, nullptr, BB * LL, 384, 512);

    // 7. pool + final
    pool_re<<<BB, 256, 0, stream>>>(u_q, u_a, b1, b2, re);
    final_k<<<BB, 64, 0, stream>>>(re, Wd, bd, out);
}

// Round 4
// 309.250 us; speedup vs baseline: 3.2024x; 1.4411x over previous
//
#include <hip/hip_runtime.h>
#include <hip/hip_bf16.h>
#include <math.h>

// Problem constants
#define NN 8192
#define HH 256
#define BB 64
#define LL 128
#define SPLITK 8

typedef __attribute__((ext_vector_type(8))) short short8v;   // 8 bf16
typedef __attribute__((ext_vector_type(4))) short short4v;   // 4 bf16
typedef __attribute__((ext_vector_type(4))) float f32x4;     // MFMA acc

static __device__ inline short bf16bits(float f) {
    __hip_bfloat16 h = __float2bfloat16(f);
    return __builtin_bit_cast(short, h);
}
static __device__ inline float bits2f(short s) {
    __hip_bfloat16 h = __builtin_bit_cast(__hip_bfloat16, s);
    return __bfloat162float(h);
}
static __device__ inline short8v cvt8(float4 f0, float4 f1) {
    short8v r;
    r[0] = bf16bits(f0.x); r[1] = bf16bits(f0.y);
    r[2] = bf16bits(f0.z); r[3] = bf16bits(f0.w);
    r[4] = bf16bits(f1.x); r[5] = bf16bits(f1.y);
    r[6] = bf16bits(f1.z); r[7] = bf16bits(f1.w);
    return r;
}
// async global -> LDS, 16 B/lane, linear dest (wave-uniform base + lane*16)
static __device__ inline void glds16(const void* src, void* lds) {
    __builtin_amdgcn_global_load_lds(
        (const __attribute__((address_space(1))) void*)src,
        (__attribute__((address_space(3))) void*)lds, 16, 0, 0);
}

// Swizzle conventions (read applies same XOR as pre-swizzled store):
//  SW32  (rows consumed in [*][32]-short LDS tiles): k ^= (row&3)<<3
//  SW128 (rows of >=128 shorts, LDS-resident whole): k ^= (row&7)<<3

// ---------------------------------------------------------------------------
// emb [8192][256] f32 -> embT [256][8192] bf16, SW32 pre-swizzled
// ---------------------------------------------------------------------------
__global__ __launch_bounds__(256) void transpose_emb(
    const float* __restrict__ emb, short* __restrict__ embT)
{
    __shared__ short tile[64][65];
    const int k0 = blockIdx.x * 64;   // grid.x = 128
    const int h0 = blockIdx.y * 64;   // grid.y = 4
    const int t = threadIdx.x;
#pragma unroll
    for (int i = 0; i < 16; i++) {
        int idx = t + i * 256;
        int k = idx >> 6, h = idx & 63;
        tile[h][k] = bf16bits(emb[(long)(k0 + k) * 256 + h0 + h]);
    }
    __syncthreads();
#pragma unroll
    for (int i = 0; i < 16; i++) {
        int idx = t + i * 256;
        int h = idx >> 6, k = idx & 63;
        int n = h0 + h;
        int kk = (k0 + k) ^ ((n & 3) << 3);   // SW32
        embT[(long)n * NN + kk] = tile[h][k];
    }
}

// ---------------------------------------------------------------------------
// pack weights to bf16 B^T, SW32 pre-swizzled
// ---------------------------------------------------------------------------
__global__ void pack_w(const float* __restrict__ Wc, short* __restrict__ Wcb,
                       const float* __restrict__ W1, const float* __restrict__ W2,
                       short* __restrict__ WcatT)
{
    int i = blockIdx.x * blockDim.x + threadIdx.x;
    if (i < 256 * 256) {
        int n = i >> 8, c = i & 255;
        Wcb[n * 256 + (c ^ ((n & 3) << 3))] = bf16bits(Wc[i]);
    }
    if (i < 384 * 512) {
        int n = i >> 9, d = i & 511;
        float v;
        if (n < 128)      v = W1[n * 512 + d];
        else if (n < 256) v = W2[(n - 128) * 1024 + d];
        else              v = W2[(n - 256) * 1024 + 512 + d];
        WcatT[n * 512 + (d ^ ((n & 3) << 3))] = bf16bits(v);
    }
}

// ---------------------------------------------------------------------------
// Unified bf16-MFMA GEMM. A: f32 (cvt in-flight) or bf16, optional gather.
// B: bf16 B^T [N][Kd], SW32 pre-swizzled global. LDS dbuf, padded A tile.
// EPI: 0 = Part f32 (layer1 splitK), 1 = gram (bias+relu -> Xbf16 + XT),
//      2 = plain f32 C (encoder).
// ---------------------------------------------------------------------------
template<int BM, int NW, int SK, int ABF16, int GATHER, int EPI>
__global__ __launch_bounds__(BM * 4) void gemm_mfma(
    const void* __restrict__ Ag_, const short* __restrict__ Bt,
    float* __restrict__ Cf, short* __restrict__ Cb, short* __restrict__ Ct,
    const float* __restrict__ bias, const int* __restrict__ rowidx,
    int M, int N, int Kd)
{
    constexpr int BN = NW * 4;
    constexpr int NB = NW / 16;
    constexpr int NTHR = BM * 4;
    constexpr int BCALLS = BN / BM;
    constexpr int AST = 40;              // padded A row stride (shorts)

    __shared__ short As[2][BM * AST];
    __shared__ short Bs[2][BN * 32];

    const int tid = threadIdx.x;
    const int wave = tid >> 6, lane = tid & 63;
    const int wr = wave >> 2, wc = wave & 3;
    const int r16 = lane & 15, kg = lane >> 4;

    int bid = blockIdx.x, mt, sk;
    if (SK > 1) { sk = bid & (SK - 1); mt = bid >> 3; }   // XCD-chunked decode
    else        { sk = 0; mt = bid; }
    const int m0 = mt * BM;
    const int KS = Kd / SK;
    const int kbeg = sk * KS;
    const int niter = KS / 32;

    const int arow = tid >> 2;
    const int akc = (tid & 3) * 8;
    long arow_g;
    { int r = GATHER ? rowidx[m0 + arow] : (m0 + arow); arow_g = (long)r * Kd; }

    const float* Af = (const float*)Ag_;
    const short* Ab = (const short*)Ag_;
    short* aslot0 = &As[0][arow * AST + akc];
    short* aslot1 = &As[1][arow * AST + akc];

    f32x4 acc[4][NB] = {};

    // ---- prologue: stage kstep 0 into buf 0
#pragma unroll
    for (int c = 0; c < BCALLS; c++) {
        int chunk = c * NTHR + tid;
        int n = chunk >> 2, kc = (chunk & 3) * 8;
        glds16(Bt + (long)n * Kd + kbeg + kc, &Bs[0][(c * NTHR + wave * 64) * 8]);
    }
    if (ABF16) {
        *(short8v*)aslot0 = *(const short8v*)(Ab + arow_g + kbeg + akc);
    } else {
        const float* ap = Af + arow_g + kbeg + akc;
        *(short8v*)aslot0 = cvt8(*(const float4*)ap, *(const float4*)(ap + 4));
    }
    __syncthreads();

    int cur = 0;
    for (int t = 0; t < niter; t++) {
        const int nxt = cur ^ 1;
        const bool more = (t + 1 < niter);
        short8v areg;
        float4 f0, f1;
        if (more) {
            const int kt = kbeg + (t + 1) * 32;
            if (ABF16) areg = *(const short8v*)(Ab + arow_g + kt + akc);
            else {
                const float* ap = Af + arow_g + kt + akc;
                f0 = *(const float4*)ap; f1 = *(const float4*)(ap + 4);
            }
#pragma unroll
            for (int c = 0; c < BCALLS; c++) {
                int chunk = c * NTHR + tid;
                int n = chunk >> 2, kc = (chunk & 3) * 8;
                glds16(Bt + (long)n * Kd + kt + kc,
                       &Bs[nxt][(c * NTHR + wave * 64) * 8]);
            }
        }

        short8v a[4], b[NB];
#pragma unroll
        for (int i = 0; i < 4; i++)
            a[i] = *(const short8v*)&As[cur][(wr * 64 + i * 16 + r16) * AST + kg * 8];
#pragma unroll
        for (int j = 0; j < NB; j++) {
            int n = wc * NW + j * 16 + r16;
            b[j] = *(const short8v*)&Bs[cur][n * 32 + ((kg * 8) ^ ((n & 3) << 3))];
        }
#pragma unroll
        for (int i = 0; i < 4; i++)
#pragma unroll
            for (int j = 0; j < NB; j++)
                acc[i][j] = __builtin_amdgcn_mfma_f32_16x16x32_bf16(
                    a[i], b[j], acc[i][j], 0, 0, 0);

        if (more) {
            if (ABF16) *(short8v*)(nxt ? aslot1 : aslot0) = areg;
            else       *(short8v*)(nxt ? aslot1 : aslot0) = cvt8(f0, f1);
        }
        __syncthreads();
        cur = nxt;
    }

    // ---- epilogue
    if (EPI == 0) {
        float* P = Cf + (long)sk * M * N;
#pragma unroll
        for (int i = 0; i < 4; i++)
#pragma unroll
            for (int j = 0; j < NB; j++) {
                int col = wc * NW + j * 16 + r16;
#pragma unroll
                for (int r = 0; r < 4; r++) {
                    int row = m0 + wr * 64 + i * 16 + kg * 4 + r;
                    P[(long)row * N + col] = acc[i][j][r];
                }
            }
    } else if (EPI == 2) {
#pragma unroll
        for (int i = 0; i < 4; i++)
#pragma unroll
            for (int j = 0; j < NB; j++) {
                int col = wc * NW + j * 16 + r16;
#pragma unroll
                for (int r = 0; r < 4; r++) {
                    int row = m0 + wr * 64 + i * 16 + kg * 4 + r;
                    Cf[(long)row * N + col] = acc[i][j][r];
                }
            }
    } else {   // EPI == 1: gram -> X bf16 (SW128) + XT bf16 (SW128)
#pragma unroll
        for (int i = 0; i < 4; i++)
#pragma unroll
            for (int j = 0; j < NB; j++) {
                int col = wc * NW + j * 16 + r16;
                float bv = bias[col];
                float vr[4];
#pragma unroll
                for (int r = 0; r < 4; r++)
                    vr[r] = fmaxf(acc[i][j][r] + bv, 0.f);
                int rbase = m0 + wr * 64 + i * 16 + kg * 4;
                int bb = rbase >> 7;
                int lbase = rbase & 127;
#pragma unroll
                for (int r = 0; r < 4; r++) {
                    int grow = rbase + r;
                    Cb[(long)grow * 256 + (col ^ ((grow & 7) << 3))] = bf16bits(vr[r]);
                }
                short4v t4;
#pragma unroll
                for (int r = 0; r < 4; r++) t4[r] = bf16bits(vr[r]);
                int lsw = lbase ^ ((col & 7) << 3);
                *(short4v*)&Ct[(long)bb * (256 * 128) + col * 128 + lsw] = t4;
            }
    }
}

// ---------------------------------------------------------------------------
// layer1 partial reduce -> bf16 (plain row-major; gram re-stages with pad)
// ---------------------------------------------------------------------------
__global__ __launch_bounds__(256) void reduceK(
    const float* __restrict__ P, short* __restrict__ out)
{
    const long n = (long)NN * HH;
    long i = ((long)blockIdx.x * 256 + threadIdx.x) * 4;
    if (i >= n) return;
    float4 s = *(const float4*)&P[i];
#pragma unroll
    for (int k = 1; k < SPLITK; k++) {
        float4 v = *(const float4*)&P[(long)k * n + i];
        s.x += v.x; s.y += v.y; s.z += v.z; s.w += v.w;
    }
    short4v o;
    o[0] = bf16bits(s.x); o[1] = bf16bits(s.y);
    o[2] = bf16bits(s.z); o[3] = bf16bits(s.w);
    *(short4v*)&out[i] = o;
}

// ---------------------------------------------------------------------------
// qkT: per batch b, s[q][k] = Qm[b,q,:] . Am[b,k,:]  (bf16 MFMA, f32 out)
// ---------------------------------------------------------------------------
__global__ __launch_bounds__(256) void qkT(
    const short* __restrict__ Qb16, const short* __restrict__ Ab16,
    float* __restrict__ s)
{
    __shared__ short Q[128 * 256];
    __shared__ short Am[128 * 256];
    const int b = blockIdx.x;
    const int tid = threadIdx.x, wave = tid >> 6, lane = tid & 63;
    const int r16 = lane & 15, kg = lane >> 4;
    const long boff = (long)b * 128 * 256;

#pragma unroll
    for (int c = 0; c < 16; c++) {
        glds16(Qb16 + boff + ((long)c * 256 + tid) * 8, &Q[(c * 256 + wave * 64) * 8]);
        glds16(Ab16 + boff + ((long)c * 256 + tid) * 8, &Am[(c * 256 + wave * 64) * 8]);
    }
    __syncthreads();

    f32x4 acc[2][8] = {};
    const int q0 = wave * 32;
#pragma unroll
    for (int ks = 0; ks < 8; ks++) {
        short8v a[2], bf[8];
#pragma unroll
        for (int i = 0; i < 2; i++) {
            int q = q0 + i * 16 + r16;
            a[i] = *(const short8v*)&Q[q * 256 + ((ks * 32 + kg * 8) ^ ((q & 7) << 3))];
        }
#pragma unroll
        for (int j = 0; j < 8; j++) {
            int n = j * 16 + r16;
            bf[j] = *(const short8v*)&Am[n * 256 + ((ks * 32 + kg * 8) ^ ((n & 7) << 3))];
        }
#pragma unroll
        for (int i = 0; i < 2; i++)
#pragma unroll
            for (int j = 0; j < 8; j++)
                acc[i][j] = __builtin_amdgcn_mfma_f32_16x16x32_bf16(
                    a[i], bf[j], acc[i][j], 0, 0, 0);
    }

    float* sp = s + (long)b * 16384;
#pragma unroll
    for (int i = 0; i < 2; i++)
#pragma unroll
        for (int j = 0; j < 8; j++)
#pragma unroll
            for (int r = 0; r < 4; r++) {
                int q = q0 + i * 16 + kg * 4 + r;
                int k = j * 16 + r16;
                sp[q * 128 + k] = acc[i][j][r];
            }
}

// ---------------------------------------------------------------------------
// attn_pv<TRANS>: softmax of s rows (TRANS=0) or cols (TRANS=1) -> P,
// E = P @ XT^T via MFMA, then fused t-features:
// t[row][col] = (x-E)^2, t[row][256+col] = x*E   (x from Xrow bf16)
// ---------------------------------------------------------------------------
template<int TRANS>
__global__ __launch_bounds__(256) void attn_pv(
    const float* __restrict__ s, const short* __restrict__ XT,
    const short* __restrict__ Xrow, float* __restrict__ tout)
{
    __shared__ float sm[128 * 128];   // 64 KB; reused for XT after softmax
    __shared__ short P[128 * 128];    // 32 KB
    short* XL = (short*)sm;
    const int b = blockIdx.x;
    const int tid = threadIdx.x, wave = tid >> 6, lane = tid & 63;
    const int r16 = lane & 15, kg = lane >> 4;

#pragma unroll
    for (int c = 0; c < 16; c++)
        glds16(s + (long)b * 16384 + ((long)c * 256 + tid) * 4,
               &sm[(c * 256 + wave * 64) * 4]);
    __syncthreads();

    if (tid < 128) {
        const int t = tid;
        float mx = -1e30f;
        if (TRANS == 0) {
            for (int i = 0; i < 128; i++)
                mx = fmaxf(mx, sm[t * 128 + ((i + t) & 127)]);
            float sum = 0.f;
            for (int i = 0; i < 128; i++)
                sum += expf(sm[t * 128 + ((i + t) & 127)] - mx);
            float inv = 1.f / sum;
            for (int i = 0; i < 128; i++) {
                int k = (i + t) & 127;
                float p = expf(sm[t * 128 + k] - mx) * inv;
                P[t * 128 + (k ^ ((t & 7) << 3))] = bf16bits(p);
            }
        } else {
            for (int i = 0; i < 128; i++)
                mx = fmaxf(mx, sm[i * 128 + t]);
            float sum = 0.f;
            for (int i = 0; i < 128; i++)
                sum += expf(sm[i * 128 + t] - mx);
            float inv = 1.f / sum;
            for (int i = 0; i < 128; i++) {
                float p = expf(sm[i * 128 + t] - mx) * inv;
                P[t * 128 + (i ^ ((t & 7) << 3))] = bf16bits(p);
            }
        }
    }
    __syncthreads();

    // stage XT (overwrites sm)
#pragma unroll
    for (int c = 0; c < 16; c++)
        glds16(XT + (long)b * 32768 + ((long)c * 256 + tid) * 8,
               &XL[(c * 256 + wave * 64) * 8]);
    __syncthreads();

    f32x4 acc[8][4] = {};
#pragma unroll
    for (int ks = 0; ks < 4; ks++) {
        short8v a[8], bf[4];
#pragma unroll
        for (int i = 0; i < 8; i++) {
            int row = i * 16 + r16;
            a[i] = *(const short8v*)&P[row * 128 + ((ks * 32 + kg * 8) ^ ((row & 7) << 3))];
        }
#pragma unroll
        for (int j = 0; j < 4; j++) {
            int h = wave * 64 + j * 16 + r16;
            bf[j] = *(const short8v*)&XL[h * 128 + ((ks * 32 + kg * 8) ^ ((h & 7) << 3))];
        }
#pragma unroll
        for (int i = 0; i < 8; i++)
#pragma unroll
            for (int j = 0; j < 4; j++)
                acc[i][j] = __builtin_amdgcn_mfma_f32_16x16x32_bf16(
                    a[i], bf[j], acc[i][j], 0, 0, 0);
    }

    float* tp = tout + (long)b * 128 * 512;
    const short* xr = Xrow + (long)b * 128 * 256;
#pragma unroll
    for (int i = 0; i < 8; i++)
#pragma unroll
        for (int j = 0; j < 4; j++) {
            int col = wave * 64 + j * 16 + r16;
#pragma unroll
            for (int r = 0; r < 4; r++) {
                int row = i * 16 + kg * 4 + r;
                float E = acc[i][j][r];
                float x = bits2f(xr[row * 256 + (col ^ ((row & 7) << 3))]);
                float d = x - E;
                tp[(long)row * 512 + col] = d * d;
                tp[(long)row * 512 + 256 + col] = x * E;
            }
        }
}

// ---------------------------------------------------------------------------
__global__ __launch_bounds__(256) void pool_re(
    const float* __restrict__ u_q, const float* __restrict__ u_a,
    const float* __restrict__ b1, const float* __restrict__ b2,
    float* __restrict__ re)
{
    const int b = blockIdx.x;
    const int t = threadIdx.x;
#pragma unroll
    for (int side = 0; side < 2; side++) {
        const float* uu = side ? u_a : u_q;
        if (t < 128) {
            int k = t;
            float bias = b1[k];
            float mx = -1e30f;
            for (int l = 0; l < 128; l++) {
                float v = uu[((long)b * 128 + l) * 384 + k] + bias;
                mx = fmaxf(mx, v);
            }
            re[b * 512 + side * 256 + k] = fmaxf(mx, 0.f);
        } else {
            int k = t - 128;
            float bias = b2[k];
            float mx = -1e30f;
            for (int l = 0; l < 127; l++) {
                float v = uu[((long)b * 128 + l) * 384 + 128 + k]
                        + uu[((long)b * 128 + l + 1) * 384 + 256 + k] + bias;
                mx = fmaxf(mx, v);
            }
            re[b * 512 + side * 256 + 128 + k] = fmaxf(mx, 0.f);
        }
    }
}

// ---------------------------------------------------------------------------
__global__ __launch_bounds__(64) void final_k(
    const float* __restrict__ re, const float* __restrict__ Wd,
    const float* __restrict__ bd, float* __restrict__ out)
{
    const int b = blockIdx.x;
    const int t = threadIdx.x;
    float p0 = 0.f, p1 = 0.f;
    for (int d = t; d < 512; d += 64) {
        float r = re[b * 512 + d];
        p0 = fmaf(r, Wd[d], p0);
        p1 = fmaf(r, Wd[512 + d], p1);
    }
#pragma unroll
    for (int off = 32; off; off >>= 1) {
        p0 += __shfl_xor(p0, off);
        p1 += __shfl_xor(p1, off);
    }
    if (t == 0) {
        float l0 = p0 + bd[0], l1 = p1 + bd[1];
        float m = fmaxf(l0, l1);
        float lse = m + logf(expf(l0 - m) + expf(l1 - m));
        out[b * 2 + 0] = l0 - lse;
        out[b * 2 + 1] = l1 - lse;
    }
}

// ---------------------------------------------------------------------------
extern "C" void kernel_launch(void* const* d_in, const int* in_sizes, int n_in,
                              void* d_out, int out_size, void* d_ws, size_t ws_size,
                              hipStream_t stream)
{
    const float* A    = (const float*)d_in[0];
    const float* emb  = (const float*)d_in[1];
    const float* Wc   = (const float*)d_in[2];
    const float* bc   = (const float*)d_in[3];
    const float* W1   = (const float*)d_in[4];
    const float* b1   = (const float*)d_in[5];
    const float* W2   = (const float*)d_in[6];
    const float* b2   = (const float*)d_in[7];
    const float* Wd   = (const float*)d_in[8];
    const float* bd   = (const float*)d_in[9];
    const int* q_idx  = (const int*)d_in[10];
    const int* a_idx  = (const int*)d_in[11];
    float* out = (float*)d_out;
    float* ws  = (float*)d_ws;

    // workspace layout (float units; ws >= 1 GB per harness fill)
    const long SZ_L1 = (long)NN * HH;                 // 2M
    float* Part   = ws;                               // 8 x [8192][256] f32 (16M f)
    float* p      = Part + (long)SPLITK * SZ_L1;
    short* l1b    = (short*)p;          p += SZ_L1 / 2 + 1024;   // bf16 [8192][256]
    short* Wcb    = (short*)p;          p += 32768 + 1024;       // bf16 [256][256] SW32
    short* WcatT  = (short*)p;          p += 98304 + 1024;       // bf16 [384][512] SW32
    short* embT   = (short*)p;          p += SZ_L1 / 2 + 1024;   // bf16 [256][8192] SW32
    short* Qb16   = (short*)p;          p += SZ_L1 / 2 + 1024;   // bf16 [8192][256] SW128
    short* Ab16   = (short*)p;          p += SZ_L1 / 2 + 1024;
    short* QT     = (short*)p;          p += SZ_L1 / 2 + 1024;   // bf16 [64][256][128] SW128
    short* AT     = (short*)p;          p += SZ_L1 / 2 + 1024;
    float* s      = p;                  p += (long)BB * LL * LL; // f32 [64][128][128]
    float* t_q    = p;                  p += (long)BB * LL * 512;
    float* t_a    = p;                  p += (long)BB * LL * 512;
    float* u_q    = p;                  p += (long)BB * LL * 384;
    float* u_a    = p;                  p += (long)BB * LL * 384;
    float* re     = p;                  p += BB * 512;

    // 1. weight packing (SW32) + emb transpose (SW32)
    pack_w<<<768, 256, 0, stream>>>(Wc, Wcb, W1, W2, WcatT);
    transpose_emb<<<dim3(128, 4), 256, 0, stream>>>(emb, embT);

    // 2. layer1 = A @ emb: BM=128, BN=256, splitK=8, XCD-chunked 1-D grid
    gemm_mfma<128, 64, SPLITK, 0, 0, 0><<<NN / 128 * SPLITK, 512, 0, stream>>>(
        A, embT, Part, nullptr, nullptr, nullptr, nullptr, NN, HH, NN);
    reduceK<<<(int)(SZ_L1 / 4 / 256), 256, 0, stream>>>(Part, l1b);

    // 3. gram -> bf16 X (SW128) + per-batch XT (SW128), relu+bias fused
    gemm_mfma<64, 64, 1, 1, 1, 1><<<(BB * LL) / 64, 256, 0, stream>>>(
        l1b, Wcb, nullptr, Qb16, QT, bc, q_idx, BB * LL, HH, HH);
    gemm_mfma<64, 64, 1, 1, 1, 1><<<(BB * LL) / 64, 256, 0, stream>>>(
        l1b, Wcb, nullptr, Ab16, AT, bc, a_idx, BB * LL, HH, HH);

    // 4. attention: s, then softmax+PV+t-build fused (both sides)
    qkT<<<BB, 256, 0, stream>>>(Qb16, Ab16, s);
    attn_pv<0><<<BB, 256, 0, stream>>>(s, AT, Qb16, t_q);
    attn_pv<1><<<BB, 256, 0, stream>>>(s, QT, Ab16, t_a);

    // 5. encoder GEMMs: u = t @ Wcat (M=8192, N=384, K=512)
    gemm_mfma<64, 96, 1, 0, 0, 2><<<(BB * LL) / 64, 256, 0, stream>>>(
        t_q, WcatT, u_q, nullptr, nullptr, nullptr, nullptr, BB * LL, 384, 512);
    gemm_mfma<64, 96, 1, 0, 0, 2><<<(BB * LL) / 64, 256, 0, stream>>>(
        t_a, WcatT, u_a, nullptr, nullptr, nullptr, nullptr, BB * LL, 384, 512);

    // 6. pool + final
    pool_re<<<BB, 256, 0, stream>>>(u_q, u_a, b1, b2, re);
    final_k<<<BB, 64, 0, stream>>>(re, Wd, bd, out);
}

// Round 6
// 304.450 us; speedup vs baseline: 3.2529x; 1.0158x over previous
//
#include <hip/hip_runtime.h>
#include <hip/hip_bf16.h>
#include <math.h>

// Problem constants
#define NN 8192
#define HH 256
#define BB 64
#define LL 128
#define SPLITK 8

typedef __attribute__((ext_vector_type(8))) short short8v;   // 8 bf16
typedef __attribute__((ext_vector_type(4))) short short4v;   // 4 bf16
typedef __attribute__((ext_vector_type(4))) float f32x4;     // MFMA acc

static __device__ inline short bf16bits(float f) {
    __hip_bfloat16 h = __float2bfloat16(f);
    return __builtin_bit_cast(short, h);
}
static __device__ inline float bits2f(short s) {
    __hip_bfloat16 h = __builtin_bit_cast(__hip_bfloat16, s);
    return __bfloat162float(h);
}
static __device__ inline short8v cvt8(float4 f0, float4 f1) {
    short8v r;
    r[0] = bf16bits(f0.x); r[1] = bf16bits(f0.y);
    r[2] = bf16bits(f0.z); r[3] = bf16bits(f0.w);
    r[4] = bf16bits(f1.x); r[5] = bf16bits(f1.y);
    r[6] = bf16bits(f1.z); r[7] = bf16bits(f1.w);
    return r;
}
// async global -> LDS, 16 B/lane, linear dest (wave-uniform base + lane*16)
static __device__ inline void glds16(const void* src, void* lds) {
    __builtin_amdgcn_global_load_lds(
        (const __attribute__((address_space(1))) void*)src,
        (__attribute__((address_space(3))) void*)lds, 16, 0, 0);
}
template<int N> static __device__ inline void vmwait() {
    if constexpr (N == 0) asm volatile("s_waitcnt vmcnt(0)" ::: "memory");
    else if constexpr (N == 1) asm volatile("s_waitcnt vmcnt(1)" ::: "memory");
    else if constexpr (N == 2) asm volatile("s_waitcnt vmcnt(2)" ::: "memory");
    else if constexpr (N == 3) asm volatile("s_waitcnt vmcnt(3)" ::: "memory");
    else if constexpr (N == 4) asm volatile("s_waitcnt vmcnt(4)" ::: "memory");
    else if constexpr (N == 5) asm volatile("s_waitcnt vmcnt(5)" ::: "memory");
    else if constexpr (N == 6) asm volatile("s_waitcnt vmcnt(6)" ::: "memory");
    else if constexpr (N == 7) asm volatile("s_waitcnt vmcnt(7)" ::: "memory");
    else asm volatile("s_waitcnt vmcnt(8)" ::: "memory");
}
static __device__ inline void lgkm0_barrier() {
    asm volatile("s_waitcnt lgkmcnt(0)" ::: "memory");
    __builtin_amdgcn_s_barrier();
    __builtin_amdgcn_sched_barrier(0);
}

// Swizzle conventions:
//  SW32  (rows consumed in [*][32]-short LDS tiles): k ^= (row&3)<<3
//  SW128 (rows of >=128 shorts, LDS-resident whole): k ^= (row&7)<<3

// ---------------------------------------------------------------------------
// prep: emb [8192][256] f32 -> embT [256][8192] bf16 SW32 (blocks 0..511)
//       weight packing to bf16 B^T SW32 (blocks 512..1279)
// ---------------------------------------------------------------------------
__global__ __launch_bounds__(256) void prep(
    const float* __restrict__ emb, short* __restrict__ embT,
    const float* __restrict__ Wc, short* __restrict__ Wcb,
    const float* __restrict__ W1, const float* __restrict__ W2,
    short* __restrict__ WcatT)
{
    __shared__ short tile[64][65];
    const int bid = blockIdx.x;
    const int t = threadIdx.x;
    if (bid < 512) {
        const int k0 = (bid & 127) * 64, h0 = (bid >> 7) * 64;
#pragma unroll
        for (int i = 0; i < 16; i++) {
            int idx = t + i * 256;
            int k = idx >> 6, h = idx & 63;
            tile[h][k] = bf16bits(emb[(long)(k0 + k) * 256 + h0 + h]);
        }
        __syncthreads();
#pragma unroll
        for (int i = 0; i < 16; i++) {
            int idx = t + i * 256;
            int h = idx >> 6, k = idx & 63;
            int n = h0 + h;
            int kk = (k0 + k) ^ ((n & 3) << 3);   // SW32
            embT[(long)n * NN + kk] = tile[h][k];
        }
    } else {
        int i = (bid - 512) * 256 + t;
        if (i < 256 * 256) {
            int n = i >> 8, c = i & 255;
            Wcb[n * 256 + (c ^ ((n & 3) << 3))] = bf16bits(Wc[i]);
        }
        if (i < 384 * 512) {
            int n = i >> 9, d = i & 511;
            float v;
            if (n < 128)      v = W1[n * 512 + d];
            else if (n < 256) v = W2[(n - 128) * 1024 + d];
            else              v = W2[(n - 256) * 1024 + 512 + d];
            WcatT[n * 512 + (d ^ ((n & 3) << 3))] = bf16bits(v);
        }
    }
}

// ---------------------------------------------------------------------------
// Unified bf16-MFMA GEMM, 3-buffer depth-2 pipeline, counted vmcnt,
// raw barriers. A: f32 (cvt in-flight) or bf16, optional gather.
// B: bf16 B^T [N][Kd], SW32 pre-swizzled in global.
// EPI: 0 = Part f32 (layer1 splitK), 1 = gram (bias+relu -> Xbf16 + XT),
//      2 = plain f32 C (encoder).
// ---------------------------------------------------------------------------
template<int BM, int NW, int SK, int ABF16, int GATHER, int EPI>
__global__ __launch_bounds__(BM * 4, (BM == 128) ? 4 : 2) void gemm_mfma(
    const void* __restrict__ Ag_, const short* __restrict__ Bt,
    float* __restrict__ Cf, short* __restrict__ Cb, short* __restrict__ Ct,
    const float* __restrict__ bias, const int* __restrict__ rowidx,
    int M, int N, int Kd)
{
    constexpr int BN = NW * 4;
    constexpr int NB = NW / 16;
    constexpr int NTHR = BM * 4;
    constexpr int BCALLS = BN / BM;          // glds per B tile stage
    constexpr int AOPS = ABF16 ? 1 : 2;      // vmem ops per A stage
    constexpr int OPS = AOPS + BCALLS;       // vmem ops per pipeline stage
    constexpr int AST = 40;                  // padded A row stride (shorts)

    __shared__ short As[3][BM * AST];
    __shared__ short Bs[3][BN * 32];

    const int tid = threadIdx.x;
    const int wave = tid >> 6, lane = tid & 63;
    const int wr = wave >> 2, wc = wave & 3;
    const int r16 = lane & 15, kg = lane >> 4;

    int bid = blockIdx.x, mt, sk;
    if (SK > 1) { sk = bid & (SK - 1); mt = bid >> 3; }   // XCD-chunked decode
    else        { sk = 0; mt = bid; }
    const int m0 = mt * BM;
    const int KS = Kd / SK;
    const int kbeg = sk * KS;
    const int niter = KS / 32;

    const int arow = tid >> 2;
    const int akc = (tid & 3) * 8;
    long arow_g;
    { int r = GATHER ? rowidx[m0 + arow] : (m0 + arow); arow_g = (long)r * Kd; }
    const float* Af = (const float*)Ag_;
    const short* Ab = (const short*)Ag_;

    f32x4 acc[4][NB] = {};

#define STAGE_B(T, BUF)                                                        \
    {                                                                          \
        const int kt_ = kbeg + (T) * 32;                                       \
        _Pragma("unroll")                                                      \
        for (int c = 0; c < BCALLS; c++) {                                     \
            int chunk = c * NTHR + tid;                                        \
            int n_ = chunk >> 2, kc_ = (chunk & 3) * 8;                        \
            glds16(Bt + (long)n_ * Kd + kt_ + kc_,                             \
                   &Bs[BUF][(c * NTHR + wave * 64) * 8]);                      \
        }                                                                      \
    }
#define LOAD_A(T, F0, F1, AR)                                                  \
    {                                                                          \
        const int kt_ = kbeg + (T) * 32;                                       \
        if (ABF16) (AR) = *(const short8v*)(Ab + arow_g + kt_ + akc);          \
        else {                                                                 \
            const float* ap_ = Af + arow_g + kt_ + akc;                        \
            (F0) = *(const float4*)ap_; (F1) = *(const float4*)(ap_ + 4);      \
        }                                                                      \
    }
#define WRITE_A(BUF, F0, F1, AR)                                               \
    {                                                                          \
        short8v v_ = ABF16 ? (AR) : cvt8((F0), (F1));                          \
        *(short8v*)&As[BUF][arow * AST + akc] = v_;                            \
    }

    // ---- prologue: stage tiles 0 and 1
    float4 tf0, tf1, cf0, cf1;
    short8v ta, ca;
    LOAD_A(0, tf0, tf1, ta);
    STAGE_B(0, 0);
    LOAD_A(1, cf0, cf1, ca);
    STAGE_B(1, 1);
    WRITE_A(0, tf0, tf1, ta);
    vmwait<OPS>();            // drain tile-0 glds (tile-1 ops remain in flight)
    lgkm0_barrier();

    for (int t = 0; t < niter; ++t) {
        const int cur = t % 3, nw = (t + 1) % 3, ns = (t + 2) % 3;
        const bool more2 = (t + 2) < niter;
        const bool more1 = (t + 1) < niter;
        float4 nf0, nf1;
        short8v na;
        if (more2) {
            LOAD_A(t + 2, nf0, nf1, na);
            STAGE_B(t + 2, ns);
        }

        short8v a[4], b[NB];
#pragma unroll
        for (int i = 0; i < 4; i++)
            a[i] = *(const short8v*)&As[cur][(wr * 64 + i * 16 + r16) * AST + kg * 8];
#pragma unroll
        for (int j = 0; j < NB; j++) {
            int n = wc * NW + j * 16 + r16;
            b[j] = *(const short8v*)&Bs[cur][n * 32 + ((kg * 8) ^ ((n & 3) << 3))];
        }
#pragma unroll
        for (int i = 0; i < 4; i++)
#pragma unroll
            for (int j = 0; j < NB; j++)
                acc[i][j] = __builtin_amdgcn_mfma_f32_16x16x32_bf16(
                    a[i], b[j], acc[i][j], 0, 0, 0);

        if (more1) {
            WRITE_A(nw, cf0, cf1, ca);       // compiler waits these regs
            if (more2) vmwait<OPS>();        // drain tile t+1 glds only
            else       vmwait<0>();
            lgkm0_barrier();
        }
        cf0 = nf0; cf1 = nf1; ca = na;
    }
#undef STAGE_B
#undef LOAD_A
#undef WRITE_A

    // ---- epilogue
    if (EPI == 0) {
        float* P = Cf + (long)sk * M * N;
#pragma unroll
        for (int i = 0; i < 4; i++)
#pragma unroll
            for (int j = 0; j < NB; j++) {
                int col = wc * NW + j * 16 + r16;
#pragma unroll
                for (int r = 0; r < 4; r++) {
                    int row = m0 + wr * 64 + i * 16 + kg * 4 + r;
                    P[(long)row * N + col] = acc[i][j][r];
                }
            }
    } else if (EPI == 2) {
#pragma unroll
        for (int i = 0; i < 4; i++)
#pragma unroll
            for (int j = 0; j < NB; j++) {
                int col = wc * NW + j * 16 + r16;
#pragma unroll
                for (int r = 0; r < 4; r++) {
                    int row = m0 + wr * 64 + i * 16 + kg * 4 + r;
                    Cf[(long)row * N + col] = acc[i][j][r];
                }
            }
    } else {   // EPI == 1: gram -> X bf16 (SW128) + per-batch XT bf16 (SW128)
#pragma unroll
        for (int i = 0; i < 4; i++)
#pragma unroll
            for (int j = 0; j < NB; j++) {
                int col = wc * NW + j * 16 + r16;
                float bv = bias[col];
                float vr[4];
#pragma unroll
                for (int r = 0; r < 4; r++)
                    vr[r] = fmaxf(acc[i][j][r] + bv, 0.f);
                int rbase = m0 + wr * 64 + i * 16 + kg * 4;
                int bb = rbase >> 7;
                int lbase = rbase & 127;
#pragma unroll
                for (int r = 0; r < 4; r++) {
                    int grow = rbase + r;
                    Cb[(long)grow * 256 + (col ^ ((grow & 7) << 3))] = bf16bits(vr[r]);
                }
                short4v t4;
#pragma unroll
                for (int r = 0; r < 4; r++) t4[r] = bf16bits(vr[r]);
                int lsw = lbase ^ ((col & 7) << 3);
                *(short4v*)&Ct[(long)bb * (256 * 128) + col * 128 + lsw] = t4;
            }
    }
}

// ---------------------------------------------------------------------------
// layer1 partial reduce -> bf16
// ---------------------------------------------------------------------------
__global__ __launch_bounds__(256) void reduceK(
    const float* __restrict__ P, short* __restrict__ out)
{
    const long n = (long)NN * HH;
    long i = ((long)blockIdx.x * 256 + threadIdx.x) * 4;
    if (i >= n) return;
    float4 s = *(const float4*)&P[i];
#pragma unroll
    for (int k = 1; k < SPLITK; k++) {
        float4 v = *(const float4*)&P[(long)k * n + i];
        s.x += v.x; s.y += v.y; s.z += v.z; s.w += v.w;
    }
    short4v o;
    o[0] = bf16bits(s.x); o[1] = bf16bits(s.y);
    o[2] = bf16bits(s.z); o[3] = bf16bits(s.w);
    *(short4v*)&out[i] = o;
}

// ---------------------------------------------------------------------------
// qkT: per batch b, s[q][k] = Qm[b,q,:] . Am[b,k,:]  (bf16 MFMA, f32 out)
// ---------------------------------------------------------------------------
__global__ __launch_bounds__(256) void qkT(
    const short* __restrict__ Qb16, const short* __restrict__ Ab16,
    float* __restrict__ s)
{
    __shared__ short Q[128 * 256];
    __shared__ short Am[128 * 256];
    const int b = blockIdx.x;
    const int tid = threadIdx.x, wave = tid >> 6, lane = tid & 63;
    const int r16 = lane & 15, kg = lane >> 4;
    const long boff = (long)b * 128 * 256;

#pragma unroll
    for (int c = 0; c < 16; c++) {
        glds16(Qb16 + boff + ((long)c * 256 + tid) * 8, &Q[(c * 256 + wave * 64) * 8]);
        glds16(Ab16 + boff + ((long)c * 256 + tid) * 8, &Am[(c * 256 + wave * 64) * 8]);
    }
    __syncthreads();

    f32x4 acc[2][8] = {};
    const int q0 = wave * 32;
#pragma unroll
    for (int ks = 0; ks < 8; ks++) {
        short8v a[2], bf[8];
#pragma unroll
        for (int i = 0; i < 2; i++) {
            int q = q0 + i * 16 + r16;
            a[i] = *(const short8v*)&Q[q * 256 + ((ks * 32 + kg * 8) ^ ((q & 7) << 3))];
        }
#pragma unroll
        for (int j = 0; j < 8; j++) {
            int n = j * 16 + r16;
            bf[j] = *(const short8v*)&Am[n * 256 + ((ks * 32 + kg * 8) ^ ((n & 7) << 3))];
        }
#pragma unroll
        for (int i = 0; i < 2; i++)
#pragma unroll
            for (int j = 0; j < 8; j++)
                acc[i][j] = __builtin_amdgcn_mfma_f32_16x16x32_bf16(
                    a[i], bf[j], acc[i][j], 0, 0, 0);
    }

    float* sp = s + (long)b * 16384;
#pragma unroll
    for (int i = 0; i < 2; i++)
#pragma unroll
        for (int j = 0; j < 8; j++)
#pragma unroll
            for (int r = 0; r < 4; r++) {
                int q = q0 + i * 16 + kg * 4 + r;
                int k = j * 16 + r16;
                sp[q * 128 + k] = acc[i][j][r];
            }
}

// ---------------------------------------------------------------------------
// attn_pv<TRANS>: softmax of s rows (TRANS=0) or cols (TRANS=1) -> P,
// E = P @ XT^T via MFMA, fused t-features written bf16:
// t[row][col] = (x-E)^2, t[row][256+col] = x*E
// ---------------------------------------------------------------------------
template<int TRANS>
__global__ __launch_bounds__(256) void attn_pv(
    const float* __restrict__ s, const short* __restrict__ XT,
    const short* __restrict__ Xrow, short* __restrict__ tout)
{
    __shared__ float sm[128 * 128];   // 64 KB; reused for XT after softmax
    __shared__ short P[128 * 128];    // 32 KB
    short* XL = (short*)sm;
    const int b = blockIdx.x;
    const int tid = threadIdx.x, wave = tid >> 6, lane = tid & 63;
    const int r16 = lane & 15, kg = lane >> 4;

#pragma unroll
    for (int c = 0; c < 16; c++)
        glds16(s + (long)b * 16384 + ((long)c * 256 + tid) * 4,
               &sm[(c * 256 + wave * 64) * 4]);
    __syncthreads();

    if (tid < 128) {
        const int t = tid;
        float mx = -1e30f;
        if (TRANS == 0) {
            for (int i = 0; i < 128; i++)
                mx = fmaxf(mx, sm[t * 128 + ((i + t) & 127)]);
            float sum = 0.f;
            for (int i = 0; i < 128; i++)
                sum += expf(sm[t * 128 + ((i + t) & 127)] - mx);
            float inv = 1.f / sum;
            for (int i = 0; i < 128; i++) {
                int k = (i + t) & 127;
                float p = expf(sm[t * 128 + k] - mx) * inv;
                P[t * 128 + (k ^ ((t & 7) << 3))] = bf16bits(p);
            }
        } else {
            for (int i = 0; i < 128; i++)
                mx = fmaxf(mx, sm[i * 128 + t]);
            float sum = 0.f;
            for (int i = 0; i < 128; i++)
                sum += expf(sm[i * 128 + t] - mx);
            float inv = 1.f / sum;
            for (int i = 0; i < 128; i++) {
                float p = expf(sm[i * 128 + t] - mx) * inv;
                P[t * 128 + (i ^ ((t & 7) << 3))] = bf16bits(p);
            }
        }
    }
    __syncthreads();

    // stage XT (overwrites sm)
#pragma unroll
    for (int c = 0; c < 16; c++)
        glds16(XT + (long)b * 32768 + ((long)c * 256 + tid) * 8,
               &XL[(c * 256 + wave * 64) * 8]);
    __syncthreads();

    f32x4 acc[8][4] = {};
#pragma unroll
    for (int ks = 0; ks < 4; ks++) {
        short8v a[8], bf[4];
#pragma unroll
        for (int i = 0; i < 8; i++) {
            int row = i * 16 + r16;
            a[i] = *(const short8v*)&P[row * 128 + ((ks * 32 + kg * 8) ^ ((row & 7) << 3))];
        }
#pragma unroll
        for (int j = 0; j < 4; j++) {
            int h = wave * 64 + j * 16 + r16;
            bf[j] = *(const short8v*)&XL[h * 128 + ((ks * 32 + kg * 8) ^ ((h & 7) << 3))];
        }
#pragma unroll
        for (int i = 0; i < 8; i++)
#pragma unroll
            for (int j = 0; j < 4; j++)
                acc[i][j] = __builtin_amdgcn_mfma_f32_16x16x32_bf16(
                    a[i], bf[j], acc[i][j], 0, 0, 0);
    }

    short* tp = tout + (long)b * 128 * 512;
    const short* xr = Xrow + (long)b * 128 * 256;
#pragma unroll
    for (int i = 0; i < 8; i++)
#pragma unroll
        for (int j = 0; j < 4; j++) {
            int col = wave * 64 + j * 16 + r16;
#pragma unroll
            for (int r = 0; r < 4; r++) {
                int row = i * 16 + kg * 4 + r;
                float E = acc[i][j][r];
                float x = bits2f(xr[row * 256 + (col ^ ((row & 7) << 3))]);
                float d = x - E;
                tp[(long)row * 512 + col] = bf16bits(d * d);
                tp[(long)row * 512 + 256 + col] = bf16bits(x * E);
            }
        }
}

// ---------------------------------------------------------------------------
// pool + final fused: re in LDS, then log_softmax(re @ Wd^T + bd)
// ---------------------------------------------------------------------------
__global__ __launch_bounds__(256) void pool_final(
    const float* __restrict__ u_q, const float* __restrict__ u_a,
    const float* __restrict__ b1, const float* __restrict__ b2,
    const float* __restrict__ Wd, const float* __restrict__ bd,
    float* __restrict__ out)
{
    __shared__ float re[512];
    const int b = blockIdx.x;
    const int t = threadIdx.x;
#pragma unroll
    for (int side = 0; side < 2; side++) {
        const float* uu = side ? u_a : u_q;
        if (t < 128) {
            int k = t;
            float bias = b1[k];
            float mx = -1e30f;
            for (int l = 0; l < 128; l++) {
                float v = uu[((long)b * 128 + l) * 384 + k] + bias;
                mx = fmaxf(mx, v);
            }
            re[side * 256 + k] = fmaxf(mx, 0.f);
        } else {
            int k = t - 128;
            float bias = b2[k];
            float mx = -1e30f;
            for (int l = 0; l < 127; l++) {
                float v = uu[((long)b * 128 + l) * 384 + 128 + k]
                        + uu[((long)b * 128 + l + 1) * 384 + 256 + k] + bias;
                mx = fmaxf(mx, v);
            }
            re[side * 256 + 128 + k] = fmaxf(mx, 0.f);
        }
    }
    __syncthreads();
    if (t < 64) {
        float p0 = 0.f, p1 = 0.f;
        for (int d = t; d < 512; d += 64) {
            float r = re[d];
            p0 = fmaf(r, Wd[d], p0);
            p1 = fmaf(r, Wd[512 + d], p1);
        }
#pragma unroll
        for (int off = 32; off; off >>= 1) {
            p0 += __shfl_xor(p0, off);
            p1 += __shfl_xor(p1, off);
        }
        if (t == 0) {
            float l0 = p0 + bd[0], l1 = p1 + bd[1];
            float m = fmaxf(l0, l1);
            float lse = m + logf(expf(l0 - m) + expf(l1 - m));
            out[b * 2 + 0] = l0 - lse;
            out[b * 2 + 1] = l1 - lse;
        }
    }
}

// ---------------------------------------------------------------------------
extern "C" void kernel_launch(void* const* d_in, const int* in_sizes, int n_in,
                              void* d_out, int out_size, void* d_ws, size_t ws_size,
                              hipStream_t stream)
{
    const float* A    = (const float*)d_in[0];
    const float* emb  = (const float*)d_in[1];
    const float* Wc   = (const float*)d_in[2];
    const float* bc   = (const float*)d_in[3];
    const float* W1   = (const float*)d_in[4];
    const float* b1   = (const float*)d_in[5];
    const float* W2   = (const float*)d_in[6];
    const float* b2   = (const float*)d_in[7];
    const float* Wd   = (const float*)d_in[8];
    const float* bd   = (const float*)d_in[9];
    const int* q_idx  = (const int*)d_in[10];
    const int* a_idx  = (const int*)d_in[11];
    float* out = (float*)d_out;
    float* ws  = (float*)d_ws;

    // workspace layout (float units; ws >= 1 GB per harness fill)
    const long SZ_L1 = (long)NN * HH;                 // 2,097,152
    float* Part   = ws;                               // 8 x [8192][256] f32
    float* p      = Part + (long)SPLITK * SZ_L1;
    short* l1b    = (short*)p;          p += SZ_L1 / 2 + 1024;   // bf16 [8192][256]
    short* Wcb    = (short*)p;          p += 32768 + 1024;       // bf16 [256][256] SW32
    short* WcatT  = (short*)p;          p += 98304 + 1024;       // bf16 [384][512] SW32
    short* embT   = (short*)p;          p += SZ_L1 / 2 + 1024;   // bf16 [256][8192] SW32
    short* Qb16   = (short*)p;          p += SZ_L1 / 2 + 1024;   // bf16 [8192][256] SW128
    short* Ab16   = (short*)p;          p += SZ_L1 / 2 + 1024;
    short* QT     = (short*)p;          p += SZ_L1 / 2 + 1024;   // bf16 [64][256][128] SW128
    short* AT     = (short*)p;          p += SZ_L1 / 2 + 1024;
    float* s      = p;                  p += (long)BB * LL * LL; // f32 [64][128][128]
    short* t_q    = (short*)p;          p += SZ_L1 + 1024;       // bf16 [8192][512] (FIX: full size)
    short* t_a    = (short*)p;          p += SZ_L1 + 1024;       // bf16 [8192][512] (FIX: full size)
    float* u_q    = p;                  p += (long)BB * LL * 384;
    float* u_a    = p;                  p += (long)BB * LL * 384;

    // 1. weight packing + emb transpose (merged)
    prep<<<1280, 256, 0, stream>>>(emb, embT, Wc, Wcb, W1, W2, WcatT);

    // 2. layer1 = A @ emb: BM=128, BN=256, splitK=8, XCD-chunked 1-D grid
    gemm_mfma<128, 64, SPLITK, 0, 0, 0><<<NN / 128 * SPLITK, 512, 0, stream>>>(
        A, embT, Part, nullptr, nullptr, nullptr, nullptr, NN, HH, NN);
    reduceK<<<(int)(SZ_L1 / 4 / 256), 256, 0, stream>>>(Part, l1b);

    // 3. gram -> bf16 X (SW128) + per-batch XT (SW128), relu+bias fused
    gemm_mfma<64, 64, 1, 1, 1, 1><<<(BB * LL) / 64, 256, 0, stream>>>(
        l1b, Wcb, nullptr, Qb16, QT, bc, q_idx, BB * LL, HH, HH);
    gemm_mfma<64, 64, 1, 1, 1, 1><<<(BB * LL) / 64, 256, 0, stream>>>(
        l1b, Wcb, nullptr, Ab16, AT, bc, a_idx, BB * LL, HH, HH);

    // 4. attention: s, then softmax+PV+t-build fused (both sides), t in bf16
    qkT<<<BB, 256, 0, stream>>>(Qb16, Ab16, s);
    attn_pv<0><<<BB, 256, 0, stream>>>(s, AT, Qb16, t_q);
    attn_pv<1><<<BB, 256, 0, stream>>>(s, QT, Ab16, t_a);

    // 5. encoder GEMMs: u = t @ Wcat (M=8192, N=384, K=512), A in bf16
    gemm_mfma<64, 96, 1, 1, 0, 2><<<(BB * LL) / 64, 256, 0, stream>>>(
        t_q, WcatT, u_q, nullptr, nullptr, nullptr, nullptr, BB * LL, 384, 512);
    gemm_mfma<64, 96, 1, 1, 0, 2><<<(BB * LL) / 64, 256, 0, stream>>>(
        t_a, WcatT, u_a, nullptr, nullptr, nullptr, nullptr, BB * LL, 384, 512);

    // 6. pool + final (fused)
    pool_final<<<BB, 256, 0, stream>>>(u_q, u_a, b1, b2, Wd, bd, out);
}

// Round 7
// 271.291 us; speedup vs baseline: 3.6505x; 1.1222x over previous
//
#include <hip/hip_runtime.h>
#include <hip/hip_bf16.h>
#include <math.h>

// Problem constants
#define NN 8192
#define HH 256
#define BB 64
#define LL 128
#define SPLITK 8

typedef __attribute__((ext_vector_type(8))) short short8v;   // 8 bf16
typedef __attribute__((ext_vector_type(4))) short short4v;   // 4 bf16
typedef __attribute__((ext_vector_type(4))) float f32x4;     // MFMA acc

static __device__ inline short bf16bits(float f) {
    __hip_bfloat16 h = __float2bfloat16(f);
    return __builtin_bit_cast(short, h);
}
static __device__ inline float bits2f(short s) {
    __hip_bfloat16 h = __builtin_bit_cast(__hip_bfloat16, s);
    return __bfloat162float(h);
}
static __device__ inline short8v cvt8(float4 f0, float4 f1) {
    short8v r;
    r[0] = bf16bits(f0.x); r[1] = bf16bits(f0.y);
    r[2] = bf16bits(f0.z); r[3] = bf16bits(f0.w);
    r[4] = bf16bits(f1.x); r[5] = bf16bits(f1.y);
    r[6] = bf16bits(f1.z); r[7] = bf16bits(f1.w);
    return r;
}
// async global -> LDS, 16 B/lane, linear dest (wave-uniform base + lane*16)
static __device__ inline void glds16(const void* src, void* lds) {
    __builtin_amdgcn_global_load_lds(
        (const __attribute__((address_space(1))) void*)src,
        (__attribute__((address_space(3))) void*)lds, 16, 0, 0);
}
template<int N> static __device__ inline void vmwait() {
    if constexpr (N == 0)  asm volatile("s_waitcnt vmcnt(0)"  ::: "memory");
    else if constexpr (N == 1)  asm volatile("s_waitcnt vmcnt(1)"  ::: "memory");
    else if constexpr (N == 2)  asm volatile("s_waitcnt vmcnt(2)"  ::: "memory");
    else if constexpr (N == 3)  asm volatile("s_waitcnt vmcnt(3)"  ::: "memory");
    else if constexpr (N == 4)  asm volatile("s_waitcnt vmcnt(4)"  ::: "memory");
    else if constexpr (N == 5)  asm volatile("s_waitcnt vmcnt(5)"  ::: "memory");
    else if constexpr (N == 6)  asm volatile("s_waitcnt vmcnt(6)"  ::: "memory");
    else if constexpr (N == 7)  asm volatile("s_waitcnt vmcnt(7)"  ::: "memory");
    else if constexpr (N == 8)  asm volatile("s_waitcnt vmcnt(8)"  ::: "memory");
    else if constexpr (N == 9)  asm volatile("s_waitcnt vmcnt(9)"  ::: "memory");
    else if constexpr (N == 10) asm volatile("s_waitcnt vmcnt(10)" ::: "memory");
    else if constexpr (N == 11) asm volatile("s_waitcnt vmcnt(11)" ::: "memory");
    else if constexpr (N == 12) asm volatile("s_waitcnt vmcnt(12)" ::: "memory");
    else if constexpr (N == 13) asm volatile("s_waitcnt vmcnt(13)" ::: "memory");
    else if constexpr (N == 14) asm volatile("s_waitcnt vmcnt(14)" ::: "memory");
    else if constexpr (N == 15) asm volatile("s_waitcnt vmcnt(15)" ::: "memory");
    else                        asm volatile("s_waitcnt vmcnt(16)" ::: "memory");
}
static __device__ inline void lgkm0_barrier() {
    asm volatile("s_waitcnt lgkmcnt(0)" ::: "memory");
    __builtin_amdgcn_s_barrier();
    __builtin_amdgcn_sched_barrier(0);
}

// Swizzle conventions:
//  SW32  (rows consumed in [*][32]-short LDS tiles): k ^= (row&3)<<3
//  SW128 (rows of >=128 shorts, LDS-resident whole): k ^= (row&7)<<3

// ---------------------------------------------------------------------------
// prep: emb [8192][256] f32 -> embT [256][8192] bf16 SW32 (blocks 0..511)
//       weight packing to bf16 B^T SW32 (blocks 512..1279)
// ---------------------------------------------------------------------------
__global__ __launch_bounds__(256) void prep(
    const float* __restrict__ emb, short* __restrict__ embT,
    const float* __restrict__ Wc, short* __restrict__ Wcb,
    const float* __restrict__ W1, const float* __restrict__ W2,
    short* __restrict__ WcatT)
{
    __shared__ short tile[64][65];
    const int bid = blockIdx.x;
    const int t = threadIdx.x;
    if (bid < 512) {
        const int k0 = (bid & 127) * 64, h0 = (bid >> 7) * 64;
#pragma unroll
        for (int i = 0; i < 16; i++) {
            int idx = t + i * 256;
            int k = idx >> 6, h = idx & 63;
            tile[h][k] = bf16bits(emb[(long)(k0 + k) * 256 + h0 + h]);
        }
        __syncthreads();
#pragma unroll
        for (int i = 0; i < 16; i++) {
            int idx = t + i * 256;
            int h = idx >> 6, k = idx & 63;
            int n = h0 + h;
            int kk = (k0 + k) ^ ((n & 3) << 3);   // SW32
            embT[(long)n * NN + kk] = tile[h][k];
        }
    } else {
        int i = (bid - 512) * 256 + t;
        if (i < 256 * 256) {
            int n = i >> 8, c = i & 255;
            Wcb[n * 256 + (c ^ ((n & 3) << 3))] = bf16bits(Wc[i]);
        }
        if (i < 384 * 512) {
            int n = i >> 9, d = i & 511;
            float v;
            if (n < 128)      v = W1[n * 512 + d];
            else if (n < 256) v = W2[(n - 128) * 1024 + d];
            else              v = W2[(n - 256) * 1024 + 512 + d];
            WcatT[n * 512 + (d ^ ((n & 3) << 3))] = bf16bits(v);
        }
    }
}

// ---------------------------------------------------------------------------
// Unified bf16-MFMA GEMM, 4-buffer DEPTH-3 pipeline, counted vmcnt,
// raw barriers. A: f32 (cvt in-flight) or bf16, optional gather.
// B: bf16 B^T [N][Kd], SW32 pre-swizzled in global.
// EPI: 0 = Part bf16 (layer1 splitK), 1 = gram (bias+relu -> Xbf16 + XT),
//      2 = plain f32 C (encoder).
// ---------------------------------------------------------------------------
template<int BM, int NW, int SK, int ABF16, int GATHER, int EPI>
__global__ __launch_bounds__(BM * 4, (BM == 128) ? 2 : 1) void gemm_mfma(
    const void* __restrict__ Ag_, const short* __restrict__ Bt,
    float* __restrict__ Cf, short* __restrict__ Cb, short* __restrict__ Ct,
    const float* __restrict__ bias, const int* __restrict__ rowidx,
    int M, int N, int Kd)
{
    constexpr int BN = NW * 4;
    constexpr int NB = NW / 16;
    constexpr int NTHR = BM * 4;
    constexpr int BCALLS = BN / BM;          // glds per B tile stage
    constexpr int AOPS = ABF16 ? 1 : 2;      // vmem ops per A stage
    constexpr int OPS = AOPS + BCALLS;       // vmem ops per pipeline stage
    constexpr int AST = 40;                  // padded A row stride (shorts)

    __shared__ short As[4][BM * AST];
    __shared__ short Bs[4][BN * 32];

    const int tid = threadIdx.x;
    const int wave = tid >> 6, lane = tid & 63;
    const int wr = wave >> 2, wc = wave & 3;
    const int r16 = lane & 15, kg = lane >> 4;

    int bid = blockIdx.x, mt, sk;
    if (SK > 1) { sk = bid & (SK - 1); mt = bid >> 3; }   // XCD-chunked decode
    else        { sk = 0; mt = bid; }
    const int m0 = mt * BM;
    const int KS = Kd / SK;
    const int kbeg = sk * KS;
    const int niter = KS / 32;

    const int arow = tid >> 2;
    const int akc = (tid & 3) * 8;
    long arow_g;
    { int r = GATHER ? rowidx[m0 + arow] : (m0 + arow); arow_g = (long)r * Kd; }
    const float* Af = (const float*)Ag_;
    const short* Ab = (const short*)Ag_;

    f32x4 acc[4][NB] = {};

#define STAGE_B(T, BUF)                                                        \
    {                                                                          \
        const int kt_ = kbeg + (T) * 32;                                       \
        _Pragma("unroll")                                                      \
        for (int c = 0; c < BCALLS; c++) {                                     \
            int chunk = c * NTHR + tid;                                        \
            int n_ = chunk >> 2, kc_ = (chunk & 3) * 8;                        \
            glds16(Bt + (long)n_ * Kd + kt_ + kc_,                             \
                   &Bs[BUF][(c * NTHR + wave * 64) * 8]);                      \
        }                                                                      \
    }
#define LOAD_A(T, F0, F1, AR)                                                  \
    {                                                                          \
        const int kt_ = kbeg + (T) * 32;                                       \
        if (ABF16) (AR) = *(const short8v*)(Ab + arow_g + kt_ + akc);          \
        else {                                                                 \
            const float* ap_ = Af + arow_g + kt_ + akc;                        \
            (F0) = *(const float4*)ap_; (F1) = *(const float4*)(ap_ + 4);      \
        }                                                                      \
    }
#define WRITE_A(BUF, F0, F1, AR)                                               \
    {                                                                          \
        short8v v_ = ABF16 ? (AR) : cvt8((F0), (F1));                          \
        *(short8v*)&As[BUF][arow * AST + akc] = v_;                            \
    }

    // ---- prologue: stage tiles 0,1,2 into buffers 0,1,2 (depth-3)
    float4 p0f0, p0f1, c1f0, c1f1, c2f0, c2f1;
    short8v p0a, c1a, c2a;
    LOAD_A(0, p0f0, p0f1, p0a);  STAGE_B(0, 0);
    LOAD_A(1, c1f0, c1f1, c1a);  STAGE_B(1, 1);
    LOAD_A(2, c2f0, c2f1, c2a);  STAGE_B(2, 2);
    WRITE_A(0, p0f0, p0f1, p0a);
    vmwait<2 * OPS>();          // drain tile-0 glds; tiles 1,2 stay in flight
    lgkm0_barrier();

    for (int t = 0; t < niter; ++t) {
        const int cur = t & 3, nw = (t + 1) & 3, ns = (t + 3) & 3;
        float4 nf0, nf1;
        short8v na;
        if (t + 3 < niter) {
            LOAD_A(t + 3, nf0, nf1, na);
            STAGE_B(t + 3, ns);
        }

        short8v a[4], b[NB];
#pragma unroll
        for (int i = 0; i < 4; i++)
            a[i] = *(const short8v*)&As[cur][(wr * 64 + i * 16 + r16) * AST + kg * 8];
#pragma unroll
        for (int j = 0; j < NB; j++) {
            int n = wc * NW + j * 16 + r16;
            b[j] = *(const short8v*)&Bs[cur][n * 32 + ((kg * 8) ^ ((n & 3) << 3))];
        }
#pragma unroll
        for (int i = 0; i < 4; i++)
#pragma unroll
            for (int j = 0; j < NB; j++)
                acc[i][j] = __builtin_amdgcn_mfma_f32_16x16x32_bf16(
                    a[i], b[j], acc[i][j], 0, 0, 0);

        if (t + 1 < niter) {
            WRITE_A(nw, c1f0, c1f1, c1a);    // compiler auto-waits these regs
            if (t + 3 < niter)      vmwait<2 * OPS>();  // tiles t+2,t+3 in flight
            else if (t + 2 < niter) vmwait<OPS>();      // tile t+2 in flight
            else                    vmwait<0>();
            lgkm0_barrier();
        }
        c1f0 = c2f0; c1f1 = c2f1; c1a = c2a;
        c2f0 = nf0;  c2f1 = nf1;  c2a = na;
    }
#undef STAGE_B
#undef LOAD_A
#undef WRITE_A

    // ---- epilogue
    if (EPI == 0) {            // bf16 partials
        short* P = Cb + (long)sk * M * N;
#pragma unroll
        for (int i = 0; i < 4; i++)
#pragma unroll
            for (int j = 0; j < NB; j++) {
                int col = wc * NW + j * 16 + r16;
#pragma unroll
                for (int r = 0; r < 4; r++) {
                    int row = m0 + wr * 64 + i * 16 + kg * 4 + r;
                    P[(long)row * N + col] = bf16bits(acc[i][j][r]);
                }
            }
    } else if (EPI == 2) {
#pragma unroll
        for (int i = 0; i < 4; i++)
#pragma unroll
            for (int j = 0; j < NB; j++) {
                int col = wc * NW + j * 16 + r16;
#pragma unroll
                for (int r = 0; r < 4; r++) {
                    int row = m0 + wr * 64 + i * 16 + kg * 4 + r;
                    Cf[(long)row * N + col] = acc[i][j][r];
                }
            }
    } else {   // EPI == 1: gram -> X bf16 (SW128) + per-batch XT bf16 (SW128)
#pragma unroll
        for (int i = 0; i < 4; i++)
#pragma unroll
            for (int j = 0; j < NB; j++) {
                int col = wc * NW + j * 16 + r16;
                float bv = bias[col];
                float vr[4];
#pragma unroll
                for (int r = 0; r < 4; r++)
                    vr[r] = fmaxf(acc[i][j][r] + bv, 0.f);
                int rbase = m0 + wr * 64 + i * 16 + kg * 4;
                int bb = rbase >> 7;
                int lbase = rbase & 127;
#pragma unroll
                for (int r = 0; r < 4; r++) {
                    int grow = rbase + r;
                    Cb[(long)grow * 256 + (col ^ ((grow & 7) << 3))] = bf16bits(vr[r]);
                }
                short4v t4;
#pragma unroll
                for (int r = 0; r < 4; r++) t4[r] = bf16bits(vr[r]);
                int lsw = lbase ^ ((col & 7) << 3);
                *(short4v*)&Ct[(long)bb * (256 * 128) + col * 128 + lsw] = t4;
            }
    }
}

// ---------------------------------------------------------------------------
// layer1 partial reduce (bf16 partials) -> bf16
// ---------------------------------------------------------------------------
__global__ __launch_bounds__(256) void reduceK(
    const short* __restrict__ P, short* __restrict__ out)
{
    const long n = (long)NN * HH;
    long i = ((long)blockIdx.x * 256 + threadIdx.x) * 8;
    if (i >= n) return;
    float acc[8] = {};
#pragma unroll
    for (int k = 0; k < SPLITK; k++) {
        short8v v = *(const short8v*)&P[(long)k * n + i];
#pragma unroll
        for (int j = 0; j < 8; j++) acc[j] += bits2f(v[j]);
    }
    short8v o;
#pragma unroll
    for (int j = 0; j < 8; j++) o[j] = bf16bits(acc[j]);
    *(short8v*)&out[i] = o;
}

// ---------------------------------------------------------------------------
// qkT: per batch b, s[q][k] = Qm[b,q,:] . Am[b,k,:]  (bf16 MFMA, f32 out)
// ---------------------------------------------------------------------------
__global__ __launch_bounds__(256) void qkT(
    const short* __restrict__ Qb16, const short* __restrict__ Ab16,
    float* __restrict__ s)
{
    __shared__ short Q[128 * 256];
    __shared__ short Am[128 * 256];
    const int b = blockIdx.x;
    const int tid = threadIdx.x, wave = tid >> 6, lane = tid & 63;
    const int r16 = lane & 15, kg = lane >> 4;
    const long boff = (long)b * 128 * 256;

#pragma unroll
    for (int c = 0; c < 16; c++) {
        glds16(Qb16 + boff + ((long)c * 256 + tid) * 8, &Q[(c * 256 + wave * 64) * 8]);
        glds16(Ab16 + boff + ((long)c * 256 + tid) * 8, &Am[(c * 256 + wave * 64) * 8]);
    }
    __syncthreads();

    f32x4 acc[2][8] = {};
    const int q0 = wave * 32;
#pragma unroll
    for (int ks = 0; ks < 8; ks++) {
        short8v a[2], bf[8];
#pragma unroll
        for (int i = 0; i < 2; i++) {
            int q = q0 + i * 16 + r16;
            a[i] = *(const short8v*)&Q[q * 256 + ((ks * 32 + kg * 8) ^ ((q & 7) << 3))];
        }
#pragma unroll
        for (int j = 0; j < 8; j++) {
            int n = j * 16 + r16;
            bf[j] = *(const short8v*)&Am[n * 256 + ((ks * 32 + kg * 8) ^ ((n & 7) << 3))];
        }
#pragma unroll
        for (int i = 0; i < 2; i++)
#pragma unroll
            for (int j = 0; j < 8; j++)
                acc[i][j] = __builtin_amdgcn_mfma_f32_16x16x32_bf16(
                    a[i], bf[j], acc[i][j], 0, 0, 0);
    }

    float* sp = s + (long)b * 16384;
#pragma unroll
    for (int i = 0; i < 2; i++)
#pragma unroll
        for (int j = 0; j < 8; j++)
#pragma unroll
            for (int r = 0; r < 4; r++) {
                int q = q0 + i * 16 + kg * 4 + r;
                int k = j * 16 + r16;
                sp[q * 128 + k] = acc[i][j][r];
            }
}

// ---------------------------------------------------------------------------
// attn_pv<TRANS>: softmax of s rows (TRANS=0) or cols (TRANS=1) -> P,
// E = P @ XT^T via MFMA, fused t-features written bf16.
// Softmax: 2 threads per row (256 threads / 128 rows), __shfl_xor combine.
// ---------------------------------------------------------------------------
template<int TRANS>
__global__ __launch_bounds__(256) void attn_pv(
    const float* __restrict__ s, const short* __restrict__ XT,
    const short* __restrict__ Xrow, short* __restrict__ tout)
{
    __shared__ float sm[128 * 128];   // 64 KB; reused for XT after softmax
    __shared__ short P[128 * 128];    // 32 KB
    short* XL = (short*)sm;
    const int b = blockIdx.x;
    const int tid = threadIdx.x, wave = tid >> 6, lane = tid & 63;
    const int r16 = lane & 15, kg = lane >> 4;

#pragma unroll
    for (int c = 0; c < 16; c++)
        glds16(s + (long)b * 16384 + ((long)c * 256 + tid) * 4,
               &sm[(c * 256 + wave * 64) * 4]);
    __syncthreads();

    {   // wave-parallel softmax: row r = tid>>1, half = tid&1 (64 elems each)
        const int r = tid >> 1;
        const int base = (tid & 1) * 64;
        float mx = -1e30f;
#pragma unroll 8
        for (int i = 0; i < 64; i++) {
            int k = base + ((i + r) & 63);
            float v = (TRANS == 0) ? sm[r * 128 + k] : sm[k * 128 + r];
            mx = fmaxf(mx, v);
        }
        mx = fmaxf(mx, __shfl_xor(mx, 1));
        float sum = 0.f;
#pragma unroll 8
        for (int i = 0; i < 64; i++) {
            int k = base + ((i + r) & 63);
            float v = (TRANS == 0) ? sm[r * 128 + k] : sm[k * 128 + r];
            sum += __expf(v - mx);
        }
        sum += __shfl_xor(sum, 1);
        float inv = 1.f / sum;
#pragma unroll 8
        for (int i = 0; i < 64; i++) {
            int k = base + ((i + r) & 63);
            float v = (TRANS == 0) ? sm[r * 128 + k] : sm[k * 128 + r];
            P[r * 128 + (k ^ ((r & 7) << 3))] = bf16bits(__expf(v - mx) * inv);
        }
    }
    __syncthreads();

    // stage XT (overwrites sm)
#pragma unroll
    for (int c = 0; c < 16; c++)
        glds16(XT + (long)b * 32768 + ((long)c * 256 + tid) * 8,
               &XL[(c * 256 + wave * 64) * 8]);
    __syncthreads();

    f32x4 acc[8][4] = {};
#pragma unroll
    for (int ks = 0; ks < 4; ks++) {
        short8v a[8], bf[4];
#pragma unroll
        for (int i = 0; i < 8; i++) {
            int row = i * 16 + r16;
            a[i] = *(const short8v*)&P[row * 128 + ((ks * 32 + kg * 8) ^ ((row & 7) << 3))];
        }
#pragma unroll
        for (int j = 0; j < 4; j++) {
            int h = wave * 64 + j * 16 + r16;
            bf[j] = *(const short8v*)&XL[h * 128 + ((ks * 32 + kg * 8) ^ ((h & 7) << 3))];
        }
#pragma unroll
        for (int i = 0; i < 8; i++)
#pragma unroll
            for (int j = 0; j < 4; j++)
                acc[i][j] = __builtin_amdgcn_mfma_f32_16x16x32_bf16(
                    a[i], bf[j], acc[i][j], 0, 0, 0);
    }

    short* tp = tout + (long)b * 128 * 512;
    const short* xr = Xrow + (long)b * 128 * 256;
#pragma unroll
    for (int i = 0; i < 8; i++)
#pragma unroll
        for (int j = 0; j < 4; j++) {
            int col = wave * 64 + j * 16 + r16;
#pragma unroll
            for (int r = 0; r < 4; r++) {
                int row = i * 16 + kg * 4 + r;
                float E = acc[i][j][r];
                float x = bits2f(xr[row * 256 + (col ^ ((row & 7) << 3))]);
                float d = x - E;
                tp[(long)row * 512 + col] = bf16bits(d * d);
                tp[(long)row * 512 + 256 + col] = bf16bits(x * E);
            }
        }
}

// ---------------------------------------------------------------------------
// pool + final fused: re in LDS, then log_softmax(re @ Wd^T + bd)
// ---------------------------------------------------------------------------
__global__ __launch_bounds__(256) void pool_final(
    const float* __restrict__ u_q, const float* __restrict__ u_a,
    const float* __restrict__ b1, const float* __restrict__ b2,
    const float* __restrict__ Wd, const float* __restrict__ bd,
    float* __restrict__ out)
{
    __shared__ float re[512];
    const int b = blockIdx.x;
    const int t = threadIdx.x;
#pragma unroll
    for (int side = 0; side < 2; side++) {
        const float* uu = side ? u_a : u_q;
        if (t < 128) {
            int k = t;
            float bias = b1[k];
            float mx = -1e30f;
            for (int l = 0; l < 128; l++) {
                float v = uu[((long)b * 128 + l) * 384 + k] + bias;
                mx = fmaxf(mx, v);
            }
            re[side * 256 + k] = fmaxf(mx, 0.f);
        } else {
            int k = t - 128;
            float bias = b2[k];
            float mx = -1e30f;
            for (int l = 0; l < 127; l++) {
                float v = uu[((long)b * 128 + l) * 384 + 128 + k]
                        + uu[((long)b * 128 + l + 1) * 384 + 256 + k] + bias;
                mx = fmaxf(mx, v);
            }
            re[side * 256 + 128 + k] = fmaxf(mx, 0.f);
        }
    }
    __syncthreads();
    if (t < 64) {
        float p0 = 0.f, p1 = 0.f;
        for (int d = t; d < 512; d += 64) {
            float r = re[d];
            p0 = fmaf(r, Wd[d], p0);
            p1 = fmaf(r, Wd[512 + d], p1);
        }
#pragma unroll
        for (int off = 32; off; off >>= 1) {
            p0 += __shfl_xor(p0, off);
            p1 += __shfl_xor(p1, off);
        }
        if (t == 0) {
            float l0 = p0 + bd[0], l1 = p1 + bd[1];
            float m = fmaxf(l0, l1);
            float lse = m + logf(expf(l0 - m) + expf(l1 - m));
            out[b * 2 + 0] = l0 - lse;
            out[b * 2 + 1] = l1 - lse;
        }
    }
}

// ---------------------------------------------------------------------------
extern "C" void kernel_launch(void* const* d_in, const int* in_sizes, int n_in,
                              void* d_out, int out_size, void* d_ws, size_t ws_size,
                              hipStream_t stream)
{
    const float* A    = (const float*)d_in[0];
    const float* emb  = (const float*)d_in[1];
    const float* Wc   = (const float*)d_in[2];
    const float* bc   = (const float*)d_in[3];
    const float* W1   = (const float*)d_in[4];
    const float* b1   = (const float*)d_in[5];
    const float* W2   = (const float*)d_in[6];
    const float* b2   = (const float*)d_in[7];
    const float* Wd   = (const float*)d_in[8];
    const float* bd   = (const float*)d_in[9];
    const int* q_idx  = (const int*)d_in[10];
    const int* a_idx  = (const int*)d_in[11];
    float* out = (float*)d_out;
    float* ws  = (float*)d_ws;

    // workspace layout (float units; ws >= 1 GB per harness fill)
    const long SZ_L1 = (long)NN * HH;                 // 2,097,152
    float* p      = ws;
    short* Part   = (short*)p;          p += (long)SPLITK * SZ_L1 / 2;  // bf16 partials
    short* l1b    = (short*)p;          p += SZ_L1 / 2 + 1024;   // bf16 [8192][256]
    short* Wcb    = (short*)p;          p += 32768 + 1024;       // bf16 [256][256] SW32
    short* WcatT  = (short*)p;          p += 98304 + 1024;       // bf16 [384][512] SW32
    short* embT   = (short*)p;          p += SZ_L1 / 2 + 1024;   // bf16 [256][8192] SW32
    short* Qb16   = (short*)p;          p += SZ_L1 / 2 + 1024;   // bf16 [8192][256] SW128
    short* Ab16   = (short*)p;          p += SZ_L1 / 2 + 1024;
    short* QT     = (short*)p;          p += SZ_L1 / 2 + 1024;   // bf16 [64][256][128] SW128
    short* AT     = (short*)p;          p += SZ_L1 / 2 + 1024;
    float* s      = p;                  p += (long)BB * LL * LL; // f32 [64][128][128]
    short* t_q    = (short*)p;          p += SZ_L1 + 1024;       // bf16 [8192][512]
    short* t_a    = (short*)p;          p += SZ_L1 + 1024;       // bf16 [8192][512]
    float* u_q    = p;                  p += (long)BB * LL * 384;
    float* u_a    = p;                  p += (long)BB * LL * 384;

    // 1. weight packing + emb transpose (merged)
    prep<<<1280, 256, 0, stream>>>(emb, embT, Wc, Wcb, W1, W2, WcatT);

    // 2. layer1 = A @ emb: BM=128, BN=256, splitK=8, XCD-chunked 1-D grid
    gemm_mfma<128, 64, SPLITK, 0, 0, 0><<<NN / 128 * SPLITK, 512, 0, stream>>>(
        A, embT, nullptr, Part, nullptr, nullptr, nullptr, NN, HH, NN);
    reduceK<<<(int)(SZ_L1 / 8 / 256), 256, 0, stream>>>(Part, l1b);

    // 3. gram -> bf16 X (SW128) + per-batch XT (SW128), relu+bias fused
    gemm_mfma<64, 64, 1, 1, 1, 1><<<(BB * LL) / 64, 256, 0, stream>>>(
        l1b, Wcb, nullptr, Qb16, QT, bc, q_idx, BB * LL, HH, HH);
    gemm_mfma<64, 64, 1, 1, 1, 1><<<(BB * LL) / 64, 256, 0, stream>>>(
        l1b, Wcb, nullptr, Ab16, AT, bc, a_idx, BB * LL, HH, HH);

    // 4. attention: s, then softmax+PV+t-build fused (both sides), t in bf16
    qkT<<<BB, 256, 0, stream>>>(Qb16, Ab16, s);
    attn_pv<0><<<BB, 256, 0, stream>>>(s, AT, Qb16, t_q);
    attn_pv<1><<<BB, 256, 0, stream>>>(s, QT, Ab16, t_a);

    // 5. encoder GEMMs: u = t @ Wcat (M=8192, N=384, K=512), A in bf16
    gemm_mfma<64, 96, 1, 1, 0, 2><<<(BB * LL) / 64, 256, 0, stream>>>(
        t_q, WcatT, u_q, nullptr, nullptr, nullptr, nullptr, BB * LL, 384, 512);
    gemm_mfma<64, 96, 1, 1, 0, 2><<<(BB * LL) / 64, 256, 0, stream>>>(
        t_a, WcatT, u_a, nullptr, nullptr, nullptr, nullptr, BB * LL, 384, 512);

    // 6. pool + final (fused)
    pool_final<<<BB, 256, 0, stream>>>(u_q, u_a, b1, b2, Wd, bd, out);
}